// Round 5
// baseline (403.976 us; speedup 1.0000x reference)
//
#include <hip/hip_runtime.h>

#define SEQS_PER_WG 4
#define HID 128
#define NF 13
#define SLEN 128
#define NSEQ 2048
#define ZSTRIDE 232   // f16 elems per z row; 232*2=464B rows (16B aligned)
#define LOG2E 1.44269504088896340736f

typedef _Float16 half8 __attribute__((ext_vector_type(8)));
typedef float floatx4 __attribute__((ext_vector_type(4)));

__device__ __forceinline__ float fast_rcp(float x) { return __builtin_amdgcn_rcpf(x); }
__device__ __forceinline__ float fast_ex2(float x) { return __builtin_amdgcn_exp2f(x); }
// gate pre-scaled by log2(e):  sigmoid(raw) = 1/(1+2^-x)
__device__ __forceinline__ float sigm2(float x)  { return fast_rcp(1.0f + fast_ex2(-x)); }
// gate pre-scaled by 2*log2(e): tanh(raw) = 1 - 2/(1+2^x)
__device__ __forceinline__ float tanh2(float x)  { return 1.0f - 2.0f * fast_rcp(1.0f + fast_ex2(x)); }

// ---- precompute: W_eff = (W_hh + W_ih @ W_fc) * gate_scale (f16),
//                  b_eff = (b_ih+b_hh+W_ih@b_fc) * gate_scale (f32)
// Decoder recurrence for t>=1 never needs x: x_{t+1} = h_{t+1}@W_fc^T + b_fc folds in.
// gate_scale = log2e (i,f,o) or 2*log2e (g) for exp2-based activations.
__global__ __launch_bounds__(256)
void weff_kernel(const float* __restrict__ W_ih, const float* __restrict__ W_hh,
                 const float* __restrict__ b_ih, const float* __restrict__ b_hh,
                 const float* __restrict__ W_fc, const float* __restrict__ b_fc,
                 _Float16* __restrict__ w_eff, float* __restrict__ b_eff)
{
    const int idx = blockIdx.x * 256 + threadIdx.x;   // 4H*H = 65536 total
    const int n = idx >> 7, k = idx & 127;
    const float sg = ((n >> 7) == 2) ? 2.0f * LOG2E : LOG2E;
    float s = W_hh[n * HID + k];
    #pragma unroll
    for (int f = 0; f < NF; ++f) s += W_ih[n * NF + f] * W_fc[f * HID + k];
    w_eff[n * HID + k] = (_Float16)(s * sg);
    if (k == 0) {
        float bb = b_ih[n] + b_hh[n];
        #pragma unroll
        for (int f = 0; f < NF; ++f) bb += W_ih[n * NF + f] * b_fc[f];
        b_eff[n] = bb * sg;
    }
}

// 4 seqs/WG, 512 thr, 512 WGs -> 2 WGs/CU, 4 waves/SIMD (two independent
// barrier groups overlap each other's stalls).
// Seq s lives at z-row 4*s => C row quad*4+0 = seq quad: each lane owns
// exactly one (seq,unit) cell in acc[g][0]; no cross-lane ops at all.
__global__ __launch_bounds__(512, 4)
void lstm_encdec_kernel(const float* __restrict__ X,
                        const float* __restrict__ W_ih,
                        const float* __restrict__ W_hh,
                        const float* __restrict__ b_ih,
                        const float* __restrict__ b_hh,
                        const float* __restrict__ W_fc,
                        const float* __restrict__ b_fc,
                        const _Float16* __restrict__ w_eff,
                        const float* __restrict__ b_eff,
                        float* __restrict__ out)
{
    // z = [h (128) | x (13, padded to 32)] per seq slot (rows 0,4,8,12), fp16,
    // double-buffered. Other rows stay zero (MFMA A reads rows 0..15).
    __shared__ _Float16 zbuf[2][16 * ZSTRIDE];

    const int tid  = threadIdx.x;
    const int wave = tid >> 6;            // 0..7
    const int lane = tid & 63;
    const int quad = lane >> 4;           // 0..3  == this thread's seq
    const int lcol = lane & 15;
    const int unit = wave * 16 + lcol;    // hidden unit 0..127
    const int seq0 = blockIdx.x * SEQS_PER_WG;

    // ---- loop-invariant B fragments (exp2-prescaled):
    // gates[s][n] = sum_k z[s][k]*W[n][k], n = g*128+unit
    half8 Bf[4][5];
    floatx4 biasv[4];
    #pragma unroll
    for (int g = 0; g < 4; ++g) {
        const int n = g * HID + unit;
        const float sg = (g == 2) ? 2.0f * LOG2E : LOG2E;
        #pragma unroll
        for (int ks = 0; ks < 4; ++ks) {              // h part
            const float* p = W_hh + n * HID + ks * 32 + quad * 8;
            half8 v;
            #pragma unroll
            for (int j = 0; j < 8; ++j) v[j] = (_Float16)(p[j] * sg);
            Bf[g][ks] = v;
        }
        {                                             // x part (K-step 4)
            half8 v;
            #pragma unroll
            for (int j = 0; j < 8; ++j) {
                int kk = quad * 8 + j;
                v[j] = (kk < NF) ? (_Float16)(W_ih[n * NF + kk] * sg) : (_Float16)0.0f;
            }
            Bf[g][4] = v;
        }
        float b = (b_ih[n] + b_hh[n]) * sg;
        biasv[g] = (floatx4){b, b, b, b};             // first MFMA's C operand
    }

    // W_fc fragments (wave 0 only, unscaled)
    half8 Wfcf[4];
    floatx4 bfcv = (floatx4){0.0f, 0.0f, 0.0f, 0.0f};
    if (wave == 0) {
        #pragma unroll
        for (int ks = 0; ks < 4; ++ks) {
            half8 v;
            #pragma unroll
            for (int j = 0; j < 8; ++j)
                v[j] = (lcol < NF) ? (_Float16)W_fc[lcol * HID + ks * 32 + quad * 8 + j]
                                   : (_Float16)0.0f;
            Wfcf[ks] = v;
        }
        float b = (lcol < NF) ? b_fc[lcol] : 0.0f;
        bfcv = (floatx4){b, b, b, b};
    }

    // ---- init LDS: zero both buffers, then x_0
    for (int i = tid; i < 2 * 16 * ZSTRIDE; i += 512)
        ((_Float16*)zbuf)[i] = (_Float16)0.0f;
    __syncthreads();

    const bool xact = tid < SEQS_PER_WG * NF;         // 52 threads load x
    const int  xs = tid / NF, xf = tid % NF;
    const long xbase = (long)(seq0 + xs) * SLEN * NF + xf;
    if (xact) zbuf[0][4 * xs * ZSTRIDE + HID + xf] = (_Float16)X[xbase];
    __syncthreads();

    float creg = 0.0f;
    float hkeep = 0.0f;
    int p = 0;

#define GATE_MFMA(NKS, ZR)                                                     \
    half8 a[5];                                                                \
    _Pragma("unroll")                                                          \
    for (int ks = 0; ks < (NKS); ++ks)                                         \
        a[ks] = *(const half8*)&(ZR)[lcol * ZSTRIDE + ks * 32 + quad * 8];     \
    floatx4 acc[4];                                                            \
    _Pragma("unroll")                                                          \
    for (int g = 0; g < 4; ++g)                                                \
        acc[g] = __builtin_amdgcn_mfma_f32_16x16x32_f16(a[0], Bf[g][0],        \
                                                        biasv[g], 0, 0, 0);    \
    _Pragma("unroll")                                                          \
    for (int ks = 1; ks < (NKS); ++ks)                                         \
        _Pragma("unroll")                                                      \
        for (int g = 0; g < 4; ++g)                                            \
            acc[g] = __builtin_amdgcn_mfma_f32_16x16x32_f16(a[ks], Bf[g][ks],  \
                                                            acc[g], 0, 0, 0);

#define GATES_EPILOGUE(ZW)                                                     \
    {                                                                          \
        float ii = sigm2(acc[0][0]);                                           \
        float ff = sigm2(acc[1][0]);                                           \
        float gg = tanh2(acc[2][0]);                                           \
        float oo = sigm2(acc[3][0]);                                           \
        float c  = ff * creg + ii * gg;                                        \
        creg = c;                                                              \
        hkeep = oo * tanh2(c * (2.0f * LOG2E));                                \
        (ZW)[(4 * quad) * ZSTRIDE + unit] = (_Float16)hkeep;                   \
    }

    // ===================== encoder: 128 steps, 1 barrier/step =====================
    for (int t = 0; t < SLEN; ++t) {
        const int tn = (t + 1 < SLEN) ? t + 1 : SLEN - 1;
        float xpre = 0.0f;
        if (xact) xpre = X[xbase + tn * NF];

        const _Float16* zr = zbuf[p];
        _Float16* zw = zbuf[1 - p];

        GATE_MFMA(5, zr)
        GATES_EPILOGUE(zw)
        if (xact) zw[4 * xs * ZSTRIDE + HID + xf] = (_Float16)xpre;

        __syncthreads();
        p ^= 1;
    }

    // embeddings = h_n
    out[(long)(seq0 + quad) * HID + unit] = hkeep;

    float* dec = out + (long)NSEQ * HID;

    // ===================== decoder step 0: uses real x_127 (5 K-steps) ============
    {
        const _Float16* zr = zbuf[p];
        _Float16* zw = zbuf[1 - p];
        GATE_MFMA(5, zr)
        GATES_EPILOGUE(zw)
        __syncthreads();
        p ^= 1;
    }

    // ---- swap in precomputed effective weights (16 dwordx4 loads) ----
    #pragma unroll
    for (int g = 0; g < 4; ++g) {
        const int n = g * HID + unit;
        #pragma unroll
        for (int ks = 0; ks < 4; ++ks)
            Bf[g][ks] = *(const half8*)&w_eff[n * HID + ks * 32 + quad * 8];
        const float bb = b_eff[n];
        biasv[g] = (floatx4){bb, bb, bb, bb};
    }

    // ============ decoder steps 1..127: 4 K-steps, 1 barrier, FC overlapped =======
    for (int t = 1; t < SLEN; ++t) {
        const _Float16* zr = zbuf[p];
        _Float16* zw = zbuf[1 - p];

        GATE_MFMA(4, zr)

        // wave 0: dec output for step t-1 = FC(h_t); h_t IS a[0..3] (reuse, no LDS)
        if (wave == 0) {
            floatx4 o = bfcv;
            #pragma unroll
            for (int ks = 0; ks < 4; ++ks)
                o = __builtin_amdgcn_mfma_f32_16x16x32_f16(a[ks], Wfcf[ks], o, 0, 0, 0);
            if (lcol < NF)   // row quad*4+0 = seq quad, col lcol = feature
                dec[(long)(seq0 + quad) * SLEN * NF + (t - 1) * NF + lcol] = o[0];
        }

        GATES_EPILOGUE(zw)

        __syncthreads();
        p ^= 1;
    }

    // ---- final dec output: FC(h_128) from the last written buffer ----
    if (wave == 0) {
        const _Float16* zr = zbuf[p];
        half8 af[4];
        #pragma unroll
        for (int ks = 0; ks < 4; ++ks)
            af[ks] = *(const half8*)&zr[lcol * ZSTRIDE + ks * 32 + quad * 8];
        floatx4 o = bfcv;
        #pragma unroll
        for (int ks = 0; ks < 4; ++ks)
            o = __builtin_amdgcn_mfma_f32_16x16x32_f16(af[ks], Wfcf[ks], o, 0, 0, 0);
        if (lcol < NF)
            dec[(long)(seq0 + quad) * SLEN * NF + (SLEN - 1) * NF + lcol] = o[0];
    }
}

extern "C" void kernel_launch(void* const* d_in, const int* in_sizes, int n_in,
                              void* d_out, int out_size, void* d_ws, size_t ws_size,
                              hipStream_t stream) {
    const float* X    = (const float*)d_in[0];
    const float* W_ih = (const float*)d_in[1];
    const float* W_hh = (const float*)d_in[2];
    const float* b_ih = (const float*)d_in[3];
    const float* b_hh = (const float*)d_in[4];
    const float* W_fc = (const float*)d_in[5];
    const float* b_fc = (const float*)d_in[6];
    float* out = (float*)d_out;

    _Float16* w_eff = (_Float16*)d_ws;                         // 4H*H f16 = 128 KiB
    float*    b_eff = (float*)((char*)d_ws + 4 * HID * HID * sizeof(_Float16));

    weff_kernel<<<(4 * HID * HID) / 256, 256, 0, stream>>>(
        W_ih, W_hh, b_ih, b_hh, W_fc, b_fc, w_eff, b_eff);

    lstm_encdec_kernel<<<NSEQ / SEQS_PER_WG, 512, 0, stream>>>(
        X, W_ih, W_hh, b_ih, b_hh, W_fc, b_fc, w_eff, b_eff, out);
}

// Round 6
// 367.302 us; speedup vs baseline: 1.0998x; 1.0998x over previous
//
#include <hip/hip_runtime.h>

#define SEQS_PER_WG 4
#define HID 128
#define NF 13
#define SLEN 128
#define NSEQ 2048
#define ZSTRIDE 232   // f16 elems per z row; 232*2=464B rows (16B aligned)
#define LOG2E 1.44269504088896340736f

typedef _Float16 half8 __attribute__((ext_vector_type(8)));
typedef float floatx4 __attribute__((ext_vector_type(4)));

__device__ __forceinline__ float fast_rcp(float x) { return __builtin_amdgcn_rcpf(x); }
__device__ __forceinline__ float fast_ex2(float x) { return __builtin_amdgcn_exp2f(x); }
// gate pre-scaled by log2(e):  sigmoid(raw) = 1/(1+2^-x)
__device__ __forceinline__ float sigm2(float x)  { return fast_rcp(1.0f + fast_ex2(-x)); }
// gate pre-scaled by 2*log2(e): tanh(raw) = 1 - 2/(1+2^x)
__device__ __forceinline__ float tanh2(float x)  { return 1.0f - 2.0f * fast_rcp(1.0f + fast_ex2(x)); }

// ---- precompute: W_eff = (W_hh + W_ih @ W_fc) * gate_scale (f16),
//                  b_eff = (b_ih+b_hh+W_ih@b_fc) * gate_scale (f32)
// Decoder recurrence for t>=1 never needs x: x_{t+1} = h_{t+1}@W_fc^T + b_fc folds in.
// gate_scale = log2e (i,f,o) or 2*log2e (g) for exp2-based activations.
__global__ __launch_bounds__(256)
void weff_kernel(const float* __restrict__ W_ih, const float* __restrict__ W_hh,
                 const float* __restrict__ b_ih, const float* __restrict__ b_hh,
                 const float* __restrict__ W_fc, const float* __restrict__ b_fc,
                 _Float16* __restrict__ w_eff, float* __restrict__ b_eff)
{
    const int idx = blockIdx.x * 256 + threadIdx.x;   // 4H*H = 65536 total
    const int n = idx >> 7, k = idx & 127;
    const float sg = ((n >> 7) == 2) ? 2.0f * LOG2E : LOG2E;
    float s = W_hh[n * HID + k];
    #pragma unroll
    for (int f = 0; f < NF; ++f) s += W_ih[n * NF + f] * W_fc[f * HID + k];
    w_eff[n * HID + k] = (_Float16)(s * sg);
    if (k == 0) {
        float bb = b_ih[n] + b_hh[n];
        #pragma unroll
        for (int f = 0; f < NF; ++f) bb += W_ih[n * NF + f] * b_fc[f];
        b_eff[n] = bb * sg;
    }
}

// 4 seqs/WG, 512 thr, 512 WGs -> 2 WGs/CU, 4 waves/SIMD (two independent
// barrier groups overlap each other's stalls).
// __launch_bounds__(512, 2): hipcc treats arg2 as BLOCKS/CU (CUDA-style) —
// round-5's (512,4) forced 32 waves/CU -> 64-VGPR cap -> massive scratch
// spills (FETCH 64MB, WRITE 142MB). 2 blocks/CU = 16 waves/CU, VGPR cap 128:
// kernel needs ~108, no spill, and the grid only supplies 2 WGs/CU anyway.
// Seq s lives at z-row 4*s => C row quad*4+0 = seq quad: each lane owns
// exactly one (seq,unit) cell in acc[g][0]; no cross-lane ops at all.
__global__ __launch_bounds__(512, 2)
void lstm_encdec_kernel(const float* __restrict__ X,
                        const float* __restrict__ W_ih,
                        const float* __restrict__ W_hh,
                        const float* __restrict__ b_ih,
                        const float* __restrict__ b_hh,
                        const float* __restrict__ W_fc,
                        const float* __restrict__ b_fc,
                        const _Float16* __restrict__ w_eff,
                        const float* __restrict__ b_eff,
                        float* __restrict__ out)
{
    // z = [h (128) | x (13, padded to 32)] per seq slot (rows 0,4,8,12), fp16,
    // double-buffered. Other rows stay zero (MFMA A reads rows 0..15).
    __shared__ _Float16 zbuf[2][16 * ZSTRIDE];

    const int tid  = threadIdx.x;
    const int wave = tid >> 6;            // 0..7
    const int lane = tid & 63;
    const int quad = lane >> 4;           // 0..3  == this thread's seq
    const int lcol = lane & 15;
    const int unit = wave * 16 + lcol;    // hidden unit 0..127
    const int seq0 = blockIdx.x * SEQS_PER_WG;

    // ---- loop-invariant B fragments (exp2-prescaled):
    // gates[s][n] = sum_k z[s][k]*W[n][k], n = g*128+unit
    half8 Bf[4][5];
    floatx4 biasv[4];
    #pragma unroll
    for (int g = 0; g < 4; ++g) {
        const int n = g * HID + unit;
        const float sg = (g == 2) ? 2.0f * LOG2E : LOG2E;
        #pragma unroll
        for (int ks = 0; ks < 4; ++ks) {              // h part
            const float* p = W_hh + n * HID + ks * 32 + quad * 8;
            half8 v;
            #pragma unroll
            for (int j = 0; j < 8; ++j) v[j] = (_Float16)(p[j] * sg);
            Bf[g][ks] = v;
        }
        {                                             // x part (K-step 4)
            half8 v;
            #pragma unroll
            for (int j = 0; j < 8; ++j) {
                int kk = quad * 8 + j;
                v[j] = (kk < NF) ? (_Float16)(W_ih[n * NF + kk] * sg) : (_Float16)0.0f;
            }
            Bf[g][4] = v;
        }
        float b = (b_ih[n] + b_hh[n]) * sg;
        biasv[g] = (floatx4){b, b, b, b};             // first MFMA's C operand
    }

    // W_fc fragments (wave 0 only, unscaled)
    half8 Wfcf[4];
    floatx4 bfcv = (floatx4){0.0f, 0.0f, 0.0f, 0.0f};
    if (wave == 0) {
        #pragma unroll
        for (int ks = 0; ks < 4; ++ks) {
            half8 v;
            #pragma unroll
            for (int j = 0; j < 8; ++j)
                v[j] = (lcol < NF) ? (_Float16)W_fc[lcol * HID + ks * 32 + quad * 8 + j]
                                   : (_Float16)0.0f;
            Wfcf[ks] = v;
        }
        float b = (lcol < NF) ? b_fc[lcol] : 0.0f;
        bfcv = (floatx4){b, b, b, b};
    }

    // ---- init LDS: zero both buffers, then x_0
    for (int i = tid; i < 2 * 16 * ZSTRIDE; i += 512)
        ((_Float16*)zbuf)[i] = (_Float16)0.0f;
    __syncthreads();

    const bool xact = tid < SEQS_PER_WG * NF;         // 52 threads load x
    const int  xs = tid / NF, xf = tid % NF;
    const long xbase = (long)(seq0 + xs) * SLEN * NF + xf;
    if (xact) zbuf[0][4 * xs * ZSTRIDE + HID + xf] = (_Float16)X[xbase];
    __syncthreads();

    float creg = 0.0f;
    float hkeep = 0.0f;
    int p = 0;

#define GATE_MFMA(NKS, ZR)                                                     \
    half8 a[5];                                                                \
    _Pragma("unroll")                                                          \
    for (int ks = 0; ks < (NKS); ++ks)                                         \
        a[ks] = *(const half8*)&(ZR)[lcol * ZSTRIDE + ks * 32 + quad * 8];     \
    floatx4 acc[4];                                                            \
    _Pragma("unroll")                                                          \
    for (int g = 0; g < 4; ++g)                                                \
        acc[g] = __builtin_amdgcn_mfma_f32_16x16x32_f16(a[0], Bf[g][0],        \
                                                        biasv[g], 0, 0, 0);    \
    _Pragma("unroll")                                                          \
    for (int ks = 1; ks < (NKS); ++ks)                                         \
        _Pragma("unroll")                                                      \
        for (int g = 0; g < 4; ++g)                                            \
            acc[g] = __builtin_amdgcn_mfma_f32_16x16x32_f16(a[ks], Bf[g][ks],  \
                                                            acc[g], 0, 0, 0);

#define GATES_EPILOGUE(ZW)                                                     \
    {                                                                          \
        float ii = sigm2(acc[0][0]);                                           \
        float ff = sigm2(acc[1][0]);                                           \
        float gg = tanh2(acc[2][0]);                                           \
        float oo = sigm2(acc[3][0]);                                           \
        float c  = ff * creg + ii * gg;                                        \
        creg = c;                                                              \
        hkeep = oo * tanh2(c * (2.0f * LOG2E));                                \
        (ZW)[(4 * quad) * ZSTRIDE + unit] = (_Float16)hkeep;                   \
    }

    // ===================== encoder: 128 steps, 1 barrier/step =====================
    for (int t = 0; t < SLEN; ++t) {
        const int tn = (t + 1 < SLEN) ? t + 1 : SLEN - 1;
        float xpre = 0.0f;
        if (xact) xpre = X[xbase + tn * NF];

        const _Float16* zr = zbuf[p];
        _Float16* zw = zbuf[1 - p];

        GATE_MFMA(5, zr)
        GATES_EPILOGUE(zw)
        if (xact) zw[4 * xs * ZSTRIDE + HID + xf] = (_Float16)xpre;

        __syncthreads();
        p ^= 1;
    }

    // embeddings = h_n
    out[(long)(seq0 + quad) * HID + unit] = hkeep;

    float* dec = out + (long)NSEQ * HID;

    // ===================== decoder step 0: uses real x_127 (5 K-steps) ============
    {
        const _Float16* zr = zbuf[p];
        _Float16* zw = zbuf[1 - p];
        GATE_MFMA(5, zr)
        GATES_EPILOGUE(zw)
        __syncthreads();
        p ^= 1;
    }

    // ---- swap in precomputed effective weights (16 dwordx4 loads) ----
    #pragma unroll
    for (int g = 0; g < 4; ++g) {
        const int n = g * HID + unit;
        #pragma unroll
        for (int ks = 0; ks < 4; ++ks)
            Bf[g][ks] = *(const half8*)&w_eff[n * HID + ks * 32 + quad * 8];
        const float bb = b_eff[n];
        biasv[g] = (floatx4){bb, bb, bb, bb};
    }

    // ============ decoder steps 1..127: 4 K-steps, 1 barrier, FC overlapped =======
    for (int t = 1; t < SLEN; ++t) {
        const _Float16* zr = zbuf[p];
        _Float16* zw = zbuf[1 - p];

        GATE_MFMA(4, zr)

        // wave 0: dec output for step t-1 = FC(h_t); h_t IS a[0..3] (reuse, no LDS)
        if (wave == 0) {
            floatx4 o = bfcv;
            #pragma unroll
            for (int ks = 0; ks < 4; ++ks)
                o = __builtin_amdgcn_mfma_f32_16x16x32_f16(a[ks], Wfcf[ks], o, 0, 0, 0);
            if (lcol < NF)   // row quad*4+0 = seq quad, col lcol = feature
                dec[(long)(seq0 + quad) * SLEN * NF + (t - 1) * NF + lcol] = o[0];
        }

        GATES_EPILOGUE(zw)

        __syncthreads();
        p ^= 1;
    }

    // ---- final dec output: FC(h_128) from the last written buffer ----
    if (wave == 0) {
        const _Float16* zr = zbuf[p];
        half8 af[4];
        #pragma unroll
        for (int ks = 0; ks < 4; ++ks)
            af[ks] = *(const half8*)&zr[lcol * ZSTRIDE + ks * 32 + quad * 8];
        floatx4 o = bfcv;
        #pragma unroll
        for (int ks = 0; ks < 4; ++ks)
            o = __builtin_amdgcn_mfma_f32_16x16x32_f16(af[ks], Wfcf[ks], o, 0, 0, 0);
        if (lcol < NF)
            dec[(long)(seq0 + quad) * SLEN * NF + (SLEN - 1) * NF + lcol] = o[0];
    }
}

extern "C" void kernel_launch(void* const* d_in, const int* in_sizes, int n_in,
                              void* d_out, int out_size, void* d_ws, size_t ws_size,
                              hipStream_t stream) {
    const float* X    = (const float*)d_in[0];
    const float* W_ih = (const float*)d_in[1];
    const float* W_hh = (const float*)d_in[2];
    const float* b_ih = (const float*)d_in[3];
    const float* b_hh = (const float*)d_in[4];
    const float* W_fc = (const float*)d_in[5];
    const float* b_fc = (const float*)d_in[6];
    float* out = (float*)d_out;

    _Float16* w_eff = (_Float16*)d_ws;                         // 4H*H f16 = 128 KiB
    float*    b_eff = (float*)((char*)d_ws + 4 * HID * HID * sizeof(_Float16));

    weff_kernel<<<(4 * HID * HID) / 256, 256, 0, stream>>>(
        W_ih, W_hh, b_ih, b_hh, W_fc, b_fc, w_eff, b_eff);

    lstm_encdec_kernel<<<NSEQ / SEQS_PER_WG, 512, 0, stream>>>(
        X, W_ih, W_hh, b_ih, b_hh, W_fc, b_fc, w_eff, b_eff, out);
}

// Round 8
// 289.566 us; speedup vs baseline: 1.3951x; 1.2685x over previous
//
#include <hip/hip_runtime.h>

#define HID 128
#define NF 13
#define SLEN 128
#define NSEQ 2048
#define SEQS 8            // seqs per WG (one WG per CU's worth of work)
#define ZSTRIDE 232       // f16 elems per z row (464B rows)
#define GSTRIDE 516       // f32 elems per gbuf row (512 + 4 pad -> bank spread)
#define LOG2E 1.44269504088896340736f

typedef _Float16 half8 __attribute__((ext_vector_type(8)));
typedef float floatx4 __attribute__((ext_vector_type(4)));

__device__ __forceinline__ float fast_rcp(float x) { return __builtin_amdgcn_rcpf(x); }
__device__ __forceinline__ float fast_ex2(float x) { return __builtin_amdgcn_exp2f(x); }
// gate pre-scaled by log2(e):  sigmoid(raw) = 1/(1+2^-x)
__device__ __forceinline__ float sigm2(float x)  { return fast_rcp(1.0f + fast_ex2(-x)); }
// gate pre-scaled by 2*log2(e): tanh(raw) = 1 - 2/(1+2^x)
__device__ __forceinline__ float tanh2(float x)  { return 1.0f - 2.0f * fast_rcp(1.0f + fast_ex2(x)); }

// ---- precompute: W_eff = (W_hh + W_ih @ W_fc) * gate_scale (f16),
//                  b_eff = (b_ih+b_hh+W_ih@b_fc) * gate_scale (f32)
__global__ __launch_bounds__(256)
void weff_kernel(const float* __restrict__ W_ih, const float* __restrict__ W_hh,
                 const float* __restrict__ b_ih, const float* __restrict__ b_hh,
                 const float* __restrict__ W_fc, const float* __restrict__ b_fc,
                 _Float16* __restrict__ w_eff, float* __restrict__ b_eff)
{
    const int idx = blockIdx.x * 256 + threadIdx.x;   // 4H*H = 65536 total
    const int n = idx >> 7, k = idx & 127;
    const float sg = ((n >> 7) == 2) ? 2.0f * LOG2E : LOG2E;
    float s = W_hh[n * HID + k];
    #pragma unroll
    for (int f = 0; f < NF; ++f) s += W_ih[n * NF + f] * W_fc[f * HID + k];
    w_eff[n * HID + k] = (_Float16)(s * sg);
    if (k == 0) {
        float bb = b_ih[n] + b_hh[n];
        #pragma unroll
        for (int f = 0; f < NF; ++f) bb += W_ih[n * NF + f] * b_fc[f];
        b_eff[n] = bb * sg;
    }
}

// One 1024-thread WG per CU (256 WGs), 16 waves = 4 waves/SIMD in ONE barrier
// group. 8 seqs at z-rows 2s (A rows 0..15, odd rows zero -> 2x M-waste, the
// minimum possible at 8 seqs/CU). Wave w owns gate g=w>>2, column tiles
// sp=w&3 and sp+4: 2 tiles x 5 K = 10 MFMA/wave/step -> per-SIMD MFMA floor
// ~776 cy with no extra waste. Gates exchanged via padded LDS gbuf; epilogue
// is 1 (seq,unit) cell per thread (1024 cells), fully dense, no cross-lane ops.
// (1024,1): reg cap 128/wave -> whole WG resident by construction.
__global__ __launch_bounds__(1024, 1)
void lstm_encdec_kernel(const float* __restrict__ X,
                        const float* __restrict__ W_ih,
                        const float* __restrict__ W_hh,
                        const float* __restrict__ b_ih,
                        const float* __restrict__ b_hh,
                        const float* __restrict__ W_fc,
                        const float* __restrict__ b_fc,
                        const _Float16* __restrict__ w_eff,
                        const float* __restrict__ b_eff,
                        float* __restrict__ out)
{
    // z = [h(128) | x(13 pad 32)] per seq at row 2s; single buffer (phases are
    // barrier-separated: reads drain before bar1, writes land before bar2).
    __shared__ _Float16 zbuf[16 * ZSTRIDE];
    __shared__ float    gbuf[SEQS * GSTRIDE];   // raw gates [seq][g*128+unit]

    const int tid  = threadIdx.x;
    const int wave = tid >> 6;            // 0..15
    const int lane = tid & 63;
    const int quad = lane >> 4;           // 0..3
    const int lcol = lane & 15;
    const int g    = wave >> 2;           // gate 0..3
    const int sp   = wave & 3;            // subtile pair
    const int seq0 = blockIdx.x * SEQS;
    const int eseq = tid >> 7;            // epilogue cell: seq 0..7
    const int eunit= tid & 127;           //                unit 0..127
    const int col0 = g * HID + sp * 16 + lcol;   // gbuf col of tile 0 (tile1: +64)

    // ---- B fragments (exp2-prescaled): 2 tiles x 5 K-steps ----
    half8 Bf[2][5];
    floatx4 biasv[2];
    const float sg = (g == 2) ? 2.0f * LOG2E : LOG2E;
    #pragma unroll
    for (int j = 0; j < 2; ++j) {
        const int n = g * HID + sp * 16 + 64 * j + lcol;
        #pragma unroll
        for (int ks = 0; ks < 4; ++ks) {              // h part
            const float* pw = W_hh + n * HID + ks * 32 + quad * 8;
            half8 v;
            #pragma unroll
            for (int jj = 0; jj < 8; ++jj) v[jj] = (_Float16)(pw[jj] * sg);
            Bf[j][ks] = v;
        }
        {                                             // x part (K-step 4)
            half8 v;
            #pragma unroll
            for (int jj = 0; jj < 8; ++jj) {
                int kk = quad * 8 + jj;
                v[jj] = (kk < NF) ? (_Float16)(W_ih[n * NF + kk] * sg) : (_Float16)0.0f;
            }
            Bf[j][4] = v;
        }
        float b = (b_ih[n] + b_hh[n]) * sg;
        biasv[j] = (floatx4){b, b, b, b};             // first MFMA's C operand
    }

    // W_fc fragments (wave 0 only, unscaled)
    half8 Wfcf[4];
    floatx4 bfcv = (floatx4){0.0f, 0.0f, 0.0f, 0.0f};
    if (wave == 0) {
        #pragma unroll
        for (int ks = 0; ks < 4; ++ks) {
            half8 v;
            #pragma unroll
            for (int jj = 0; jj < 8; ++jj)
                v[jj] = (lcol < NF) ? (_Float16)W_fc[lcol * HID + ks * 32 + quad * 8 + jj]
                                    : (_Float16)0.0f;
            Wfcf[ks] = v;
        }
        float b = (lcol < NF) ? b_fc[lcol] : 0.0f;
        bfcv = (floatx4){b, b, b, b};
    }

    // ---- init: zero z (odd rows + x pads stay zero forever), then x_0 ----
    for (int i = tid; i < 16 * ZSTRIDE; i += 1024) zbuf[i] = (_Float16)0.0f;
    __syncthreads();
    const bool xact = tid < SEQS * NF;                // 104 loader threads
    const int  xs = tid / NF, xf = tid % NF;
    const long xbase = (long)(seq0 + xs) * SLEN * NF + xf;
    if (xact) zbuf[(2 * xs) * ZSTRIDE + HID + xf] = (_Float16)X[xbase];
    __syncthreads();

    float creg = 0.0f, hkeep = 0.0f;

#define GATE_MFMA(NKS)                                                         \
    half8 a[5];                                                                \
    _Pragma("unroll")                                                          \
    for (int ks = 0; ks < (NKS); ++ks)                                         \
        a[ks] = *(const half8*)&zbuf[lcol * ZSTRIDE + ks * 32 + quad * 8];     \
    floatx4 acc[2];                                                            \
    _Pragma("unroll")                                                          \
    for (int j = 0; j < 2; ++j)                                                \
        acc[j] = __builtin_amdgcn_mfma_f32_16x16x32_f16(a[0], Bf[j][0],        \
                                                        biasv[j], 0, 0, 0);    \
    _Pragma("unroll")                                                          \
    for (int ks = 1; ks < (NKS); ++ks)                                         \
        _Pragma("unroll")                                                      \
        for (int j = 0; j < 2; ++j)                                            \
            acc[j] = __builtin_amdgcn_mfma_f32_16x16x32_f16(a[ks], Bf[j][ks],  \
                                                            acc[j], 0, 0, 0);

    // C row = quad*4 + reg: reg 0 -> row 4q = seq 2q, reg 2 -> row 4q+2 = seq 2q+1
#define GATE_STORE                                                             \
    gbuf[(2 * quad)     * GSTRIDE + col0]      = acc[0][0];                    \
    gbuf[(2 * quad)     * GSTRIDE + col0 + 64] = acc[1][0];                    \
    gbuf[(2 * quad + 1) * GSTRIDE + col0]      = acc[0][2];                    \
    gbuf[(2 * quad + 1) * GSTRIDE + col0 + 64] = acc[1][2];

#define EPILOGUE                                                               \
    {                                                                          \
        float gi = gbuf[eseq * GSTRIDE + eunit];                               \
        float gf = gbuf[eseq * GSTRIDE + HID + eunit];                         \
        float gg = gbuf[eseq * GSTRIDE + 2 * HID + eunit];                     \
        float go = gbuf[eseq * GSTRIDE + 3 * HID + eunit];                     \
        float c  = sigm2(gf) * creg + sigm2(gi) * tanh2(gg);                   \
        creg = c;                                                              \
        hkeep = sigm2(go) * tanh2(c * (2.0f * LOG2E));                         \
        zbuf[(2 * eseq) * ZSTRIDE + eunit] = (_Float16)hkeep;                  \
    }

    // ===================== encoder: 128 steps, 2 barriers/step ====================
    for (int t = 0; t < SLEN; ++t) {
        const int tn = (t + 1 < SLEN) ? t + 1 : SLEN - 1;
        float xpre = xact ? X[xbase + tn * NF] : 0.0f;

        GATE_MFMA(5)
        GATE_STORE
        __syncthreads();          // gates ready; z reads drained
        EPILOGUE
        if (xact) zbuf[(2 * xs) * ZSTRIDE + HID + xf] = (_Float16)xpre;
        __syncthreads();          // z (h, x) ready for next step
    }

    // embeddings = h_n (one cell per thread, coalesced)
    out[(long)(seq0 + eseq) * HID + eunit] = hkeep;

    float* dec = out + (long)NSEQ * HID;

    // ============ decoder step 0: real x_127 (5 K-steps, old weights) =============
    {
        GATE_MFMA(5)
        GATE_STORE
        __syncthreads();
        EPILOGUE
        __syncthreads();
    }

    // ---- swap in precomputed effective weights (8 dwordx4 loads) ----
    #pragma unroll
    for (int j = 0; j < 2; ++j) {
        const int n = g * HID + sp * 16 + 64 * j + lcol;
        #pragma unroll
        for (int ks = 0; ks < 4; ++ks)
            Bf[j][ks] = *(const half8*)&w_eff[n * HID + ks * 32 + quad * 8];
        const float bb = b_eff[n];
        biasv[j] = (floatx4){bb, bb, bb, bb};
    }

    // ====== decoder steps 1..127: 4 K-steps, FC overlapped into MFMA phase ========
    for (int t = 1; t < SLEN; ++t) {
        GATE_MFMA(4)

        // wave 0: dec output for step t-1 = FC(h_t); h_t IS a[0..3] (no extra LDS)
        if (wave == 0) {
            floatx4 o = bfcv;
            #pragma unroll
            for (int ks = 0; ks < 4; ++ks)
                o = __builtin_amdgcn_mfma_f32_16x16x32_f16(a[ks], Wfcf[ks], o, 0, 0, 0);
            if (lcol < NF) {
                dec[(long)(seq0 + 2 * quad)     * SLEN * NF + (t - 1) * NF + lcol] = o[0];
                dec[(long)(seq0 + 2 * quad + 1) * SLEN * NF + (t - 1) * NF + lcol] = o[2];
            }
        }

        GATE_STORE
        __syncthreads();
        EPILOGUE
        __syncthreads();
    }

    // ---- final dec output: FC(h_128) ----
    if (wave == 0) {
        half8 af[4];
        #pragma unroll
        for (int ks = 0; ks < 4; ++ks)
            af[ks] = *(const half8*)&zbuf[lcol * ZSTRIDE + ks * 32 + quad * 8];
        floatx4 o = bfcv;
        #pragma unroll
        for (int ks = 0; ks < 4; ++ks)
            o = __builtin_amdgcn_mfma_f32_16x16x32_f16(af[ks], Wfcf[ks], o, 0, 0, 0);
        if (lcol < NF) {
            dec[(long)(seq0 + 2 * quad)     * SLEN * NF + (SLEN - 1) * NF + lcol] = o[0];
            dec[(long)(seq0 + 2 * quad + 1) * SLEN * NF + (SLEN - 1) * NF + lcol] = o[2];
        }
    }
}

extern "C" void kernel_launch(void* const* d_in, const int* in_sizes, int n_in,
                              void* d_out, int out_size, void* d_ws, size_t ws_size,
                              hipStream_t stream) {
    const float* X    = (const float*)d_in[0];
    const float* W_ih = (const float*)d_in[1];
    const float* W_hh = (const float*)d_in[2];
    const float* b_ih = (const float*)d_in[3];
    const float* b_hh = (const float*)d_in[4];
    const float* W_fc = (const float*)d_in[5];
    const float* b_fc = (const float*)d_in[6];
    float* out = (float*)d_out;

    _Float16* w_eff = (_Float16*)d_ws;                         // 4H*H f16 = 128 KiB
    float*    b_eff = (float*)((char*)d_ws + 4 * HID * HID * sizeof(_Float16));

    weff_kernel<<<(4 * HID * HID) / 256, 256, 0, stream>>>(
        W_ih, W_hh, b_ih, b_hh, W_fc, b_fc, w_eff, b_eff);

    lstm_encdec_kernel<<<NSEQ / SEQS, 1024, 0, stream>>>(
        X, W_ih, W_hh, b_ih, b_hh, W_fc, b_fc, w_eff, b_eff, out);
}

// Round 9
// 285.099 us; speedup vs baseline: 1.4170x; 1.0157x over previous
//
#include <hip/hip_runtime.h>

#define HID 128
#define NF 13
#define SLEN 128
#define NSEQ 2048
#define SEQS 8            // seqs per WG (one WG per CU's worth of work)
#define ZSTRIDE 232       // f16 elems per z row (464B rows; 116%32=20 bank spread)
#define TSTR 67           // f32 per gbuf tile block (67%32=3 -> bank spread)
#define GROW (8 * TSTR)   // f32 per gbuf seq row (536; 2*536%32=16 -> 2-way)
#define LOG2E 1.44269504088896340736f

typedef _Float16 half8 __attribute__((ext_vector_type(8)));
typedef float floatx4 __attribute__((ext_vector_type(4)));

__device__ __forceinline__ float fast_rcp(float x) { return __builtin_amdgcn_rcpf(x); }
__device__ __forceinline__ float fast_ex2(float x) { return __builtin_amdgcn_exp2f(x); }
// gate pre-scaled by log2(e):  sigmoid(raw) = 1/(1+2^-x)
__device__ __forceinline__ float sigm2(float x)  { return fast_rcp(1.0f + fast_ex2(-x)); }
// gate pre-scaled by 2*log2(e): tanh(raw) = 1 - 2/(1+2^x)
__device__ __forceinline__ float tanh2(float x)  { return 1.0f - 2.0f * fast_rcp(1.0f + fast_ex2(x)); }

// ---- precompute: W_eff = (W_hh + W_ih @ W_fc) * gate_scale (f16),
//                  b_eff = (b_ih+b_hh+W_ih@b_fc) * gate_scale (f32)
__global__ __launch_bounds__(256)
void weff_kernel(const float* __restrict__ W_ih, const float* __restrict__ W_hh,
                 const float* __restrict__ b_ih, const float* __restrict__ b_hh,
                 const float* __restrict__ W_fc, const float* __restrict__ b_fc,
                 _Float16* __restrict__ w_eff, float* __restrict__ b_eff)
{
    const int idx = blockIdx.x * 256 + threadIdx.x;   // 4H*H = 65536 total
    const int n = idx >> 7, k = idx & 127;
    const float sg = ((n >> 7) == 2) ? 2.0f * LOG2E : LOG2E;
    float s = W_hh[n * HID + k];
    #pragma unroll
    for (int f = 0; f < NF; ++f) s += W_ih[n * NF + f] * W_fc[f * HID + k];
    w_eff[n * HID + k] = (_Float16)(s * sg);
    if (k == 0) {
        float bb = b_ih[n] + b_hh[n];
        #pragma unroll
        for (int f = 0; f < NF; ++f) bb += W_ih[n * NF + f] * b_fc[f];
        b_eff[n] = bb * sg;
    }
}

// One 1024-thread WG per CU (256 WGs), 16 waves = 4 waves/SIMD in ONE barrier
// group. 8 seqs at z-rows 2s. Wave w owns gate g=w>>2, column tiles sp, sp+4.
// Gates exchanged via tile-padded LDS gbuf [seq][8 tiles][TSTR=67]:
//   store: (2q)*GROW + (2g)*TSTR + sp*16 + lcol  (seq str 1072%32=16,
//   tile str 67%32=3, lcol 0..15 + quad-pair 16 -> exact 2-way on all banks;
//   r8's flat-512 layout had +64 == same-bank pairs -> 2.7e7 conflicts).
// Epilogue: 1 (seq,unit) cell per thread, no cross-lane ops.
__global__ __launch_bounds__(1024, 1)
void lstm_encdec_kernel(const float* __restrict__ X,
                        const float* __restrict__ W_ih,
                        const float* __restrict__ W_hh,
                        const float* __restrict__ b_ih,
                        const float* __restrict__ b_hh,
                        const float* __restrict__ W_fc,
                        const float* __restrict__ b_fc,
                        const _Float16* __restrict__ w_eff,
                        const float* __restrict__ b_eff,
                        float* __restrict__ out)
{
    // z = [h(128) | x(13 pad 32)] per seq at row 2s; single buffer (phases are
    // barrier-separated: reads drain before bar1, writes land before bar2).
    __shared__ _Float16 zbuf[16 * ZSTRIDE];
    __shared__ float    gbuf[SEQS * GROW];      // raw gates, tile-padded

    const int tid  = threadIdx.x;
    const int wave = tid >> 6;            // 0..15
    const int lane = tid & 63;
    const int quad = lane >> 4;           // 0..3
    const int lcol = lane & 15;
    const int g    = wave >> 2;           // gate 0..3
    const int sp   = wave & 3;            // subtile pair
    const int seq0 = blockIdx.x * SEQS;
    const int eseq = tid >> 7;            // epilogue cell: seq 0..7
    const int eunit= tid & 127;           //                unit 0..127
    // gbuf addresses (see layout comment above)
    const int gsto = (2 * quad) * GROW + (2 * g) * TSTR + sp * 16 + lcol;
    const int grd  = eseq * GROW + (eunit >> 6) * TSTR + (eunit & 63);

    // ---- B fragments (exp2-prescaled): 2 tiles x 5 K-steps ----
    half8 Bf[2][5];
    floatx4 biasv[2];
    const float sg = (g == 2) ? 2.0f * LOG2E : LOG2E;
    #pragma unroll
    for (int j = 0; j < 2; ++j) {
        const int n = g * HID + sp * 16 + 64 * j + lcol;
        #pragma unroll
        for (int ks = 0; ks < 4; ++ks) {              // h part
            const float* pw = W_hh + n * HID + ks * 32 + quad * 8;
            half8 v;
            #pragma unroll
            for (int jj = 0; jj < 8; ++jj) v[jj] = (_Float16)(pw[jj] * sg);
            Bf[j][ks] = v;
        }
        {                                             // x part (K-step 4)
            half8 v;
            #pragma unroll
            for (int jj = 0; jj < 8; ++jj) {
                int kk = quad * 8 + jj;
                v[jj] = (kk < NF) ? (_Float16)(W_ih[n * NF + kk] * sg) : (_Float16)0.0f;
            }
            Bf[j][4] = v;
        }
        float b = (b_ih[n] + b_hh[n]) * sg;
        biasv[j] = (floatx4){b, b, b, b};             // first MFMA's C operand
    }

    // W_fc fragments (wave 0 only, unscaled)
    half8 Wfcf[4];
    floatx4 bfcv = (floatx4){0.0f, 0.0f, 0.0f, 0.0f};
    if (wave == 0) {
        #pragma unroll
        for (int ks = 0; ks < 4; ++ks) {
            half8 v;
            #pragma unroll
            for (int jj = 0; jj < 8; ++jj)
                v[jj] = (lcol < NF) ? (_Float16)W_fc[lcol * HID + ks * 32 + quad * 8 + jj]
                                    : (_Float16)0.0f;
            Wfcf[ks] = v;
        }
        float b = (lcol < NF) ? b_fc[lcol] : 0.0f;
        bfcv = (floatx4){b, b, b, b};
    }

    // ---- init: zero z (odd rows + x pads stay zero forever), then x_0 ----
    for (int i = tid; i < 16 * ZSTRIDE; i += 1024) zbuf[i] = (_Float16)0.0f;
    __syncthreads();
    const bool xact = tid < SEQS * NF;                // 104 loader threads
    const int  xs = tid / NF, xf = tid % NF;
    const long xbase = (long)(seq0 + xs) * SLEN * NF + xf;
    if (xact) zbuf[(2 * xs) * ZSTRIDE + HID + xf] = (_Float16)X[xbase];
    __syncthreads();

    float creg = 0.0f, hkeep = 0.0f;

#define GATE_MFMA(NKS)                                                         \
    half8 a[5];                                                                \
    _Pragma("unroll")                                                          \
    for (int ks = 0; ks < (NKS); ++ks)                                         \
        a[ks] = *(const half8*)&zbuf[lcol * ZSTRIDE + ks * 32 + quad * 8];     \
    floatx4 acc[2];                                                            \
    _Pragma("unroll")                                                          \
    for (int j = 0; j < 2; ++j)                                                \
        acc[j] = __builtin_amdgcn_mfma_f32_16x16x32_f16(a[0], Bf[j][0],        \
                                                        biasv[j], 0, 0, 0);    \
    _Pragma("unroll")                                                          \
    for (int ks = 1; ks < (NKS); ++ks)                                         \
        _Pragma("unroll")                                                      \
        for (int j = 0; j < 2; ++j)                                            \
            acc[j] = __builtin_amdgcn_mfma_f32_16x16x32_f16(a[ks], Bf[j][ks],  \
                                                            acc[j], 0, 0, 0);

    // C row = quad*4 + reg: reg 0 -> row 4q = seq 2q, reg 2 -> row 4q+2 = seq 2q+1
#define GATE_STORE                                                             \
    gbuf[gsto]              = acc[0][0];                                       \
    gbuf[gsto + TSTR]       = acc[1][0];                                       \
    gbuf[gsto + GROW]       = acc[0][2];                                       \
    gbuf[gsto + GROW + TSTR]= acc[1][2];

#define EPILOGUE                                                               \
    {                                                                          \
        float gi = gbuf[grd];                                                  \
        float gf = gbuf[grd + 2 * TSTR];                                       \
        float gg = gbuf[grd + 4 * TSTR];                                       \
        float go = gbuf[grd + 6 * TSTR];                                       \
        float c  = sigm2(gf) * creg + sigm2(gi) * tanh2(gg);                   \
        creg = c;                                                              \
        hkeep = sigm2(go) * tanh2(c * (2.0f * LOG2E));                         \
        zbuf[(2 * eseq) * ZSTRIDE + eunit] = (_Float16)hkeep;                  \
    }

    // ===================== encoder: 128 steps, 2 barriers/step ====================
    for (int t = 0; t < SLEN; ++t) {
        const int tn = (t + 1 < SLEN) ? t + 1 : SLEN - 1;
        float xpre = xact ? X[xbase + tn * NF] : 0.0f;

        GATE_MFMA(5)
        GATE_STORE
        __syncthreads();          // gates ready; z reads drained
        EPILOGUE
        if (xact) zbuf[(2 * xs) * ZSTRIDE + HID + xf] = (_Float16)xpre;
        __syncthreads();          // z (h, x) ready for next step
    }

    // embeddings = h_n (one cell per thread, coalesced)
    out[(long)(seq0 + eseq) * HID + eunit] = hkeep;

    float* dec = out + (long)NSEQ * HID;

    // ============ decoder step 0: real x_127 (5 K-steps, old weights) =============
    {
        GATE_MFMA(5)
        GATE_STORE
        __syncthreads();
        EPILOGUE
        __syncthreads();
    }

    // ---- swap in precomputed effective weights (8 dwordx4 loads) ----
    #pragma unroll
    for (int j = 0; j < 2; ++j) {
        const int n = g * HID + sp * 16 + 64 * j + lcol;
        #pragma unroll
        for (int ks = 0; ks < 4; ++ks)
            Bf[j][ks] = *(const half8*)&w_eff[n * HID + ks * 32 + quad * 8];
        const float bb = b_eff[n];
        biasv[j] = (floatx4){bb, bb, bb, bb};
    }

    // ====== decoder steps 1..127: 4 K-steps, FC overlapped into MFMA phase ========
    for (int t = 1; t < SLEN; ++t) {
        GATE_MFMA(4)

        // wave 0: dec output for step t-1 = FC(h_t); h_t IS a[0..3] (no extra LDS)
        if (wave == 0) {
            floatx4 o = bfcv;
            #pragma unroll
            for (int ks = 0; ks < 4; ++ks)
                o = __builtin_amdgcn_mfma_f32_16x16x32_f16(a[ks], Wfcf[ks], o, 0, 0, 0);
            if (lcol < NF) {
                dec[(long)(seq0 + 2 * quad)     * SLEN * NF + (t - 1) * NF + lcol] = o[0];
                dec[(long)(seq0 + 2 * quad + 1) * SLEN * NF + (t - 1) * NF + lcol] = o[2];
            }
        }

        GATE_STORE
        __syncthreads();
        EPILOGUE
        __syncthreads();
    }

    // ---- final dec output: FC(h_128) ----
    if (wave == 0) {
        half8 af[4];
        #pragma unroll
        for (int ks = 0; ks < 4; ++ks)
            af[ks] = *(const half8*)&zbuf[lcol * ZSTRIDE + ks * 32 + quad * 8];
        floatx4 o = bfcv;
        #pragma unroll
        for (int ks = 0; ks < 4; ++ks)
            o = __builtin_amdgcn_mfma_f32_16x16x32_f16(af[ks], Wfcf[ks], o, 0, 0, 0);
        if (lcol < NF) {
            dec[(long)(seq0 + 2 * quad)     * SLEN * NF + (SLEN - 1) * NF + lcol] = o[0];
            dec[(long)(seq0 + 2 * quad + 1) * SLEN * NF + (SLEN - 1) * NF + lcol] = o[2];
        }
    }
}

extern "C" void kernel_launch(void* const* d_in, const int* in_sizes, int n_in,
                              void* d_out, int out_size, void* d_ws, size_t ws_size,
                              hipStream_t stream) {
    const float* X    = (const float*)d_in[0];
    const float* W_ih = (const float*)d_in[1];
    const float* W_hh = (const float*)d_in[2];
    const float* b_ih = (const float*)d_in[3];
    const float* b_hh = (const float*)d_in[4];
    const float* W_fc = (const float*)d_in[5];
    const float* b_fc = (const float*)d_in[6];
    float* out = (float*)d_out;

    _Float16* w_eff = (_Float16*)d_ws;                         // 4H*H f16 = 128 KiB
    float*    b_eff = (float*)((char*)d_ws + 4 * HID * HID * sizeof(_Float16));

    weff_kernel<<<(4 * HID * HID) / 256, 256, 0, stream>>>(
        W_ih, W_hh, b_ih, b_hh, W_fc, b_fc, w_eff, b_eff);

    lstm_encdec_kernel<<<NSEQ / SEQS, 1024, 0, stream>>>(
        X, W_ih, W_hh, b_ih, b_hh, W_fc, b_fc, w_eff, b_eff, out);
}

// Round 12
// 246.808 us; speedup vs baseline: 1.6368x; 1.1551x over previous
//
#include <hip/hip_runtime.h>

#define HID 128
#define NF 13
#define SLEN 128
#define NSEQ 2048
#define SEQS 8            // seqs per WG
#define ZSTRIDE 232       // f16 elems per z row (464B rows)
#define LOG2E 1.44269504088896340736f

typedef _Float16 half8 __attribute__((ext_vector_type(8)));
typedef float floatx4 __attribute__((ext_vector_type(4)));

__device__ __forceinline__ float fast_rcp(float x) { return __builtin_amdgcn_rcpf(x); }
__device__ __forceinline__ float fast_ex2(float x) { return __builtin_amdgcn_exp2f(x); }
// gate pre-scaled by log2(e):  sigmoid(raw) = 1/(1+2^-x)
__device__ __forceinline__ float sigm2(float x)  { return fast_rcp(1.0f + fast_ex2(-x)); }
// gate pre-scaled by 2*log2(e): tanh(raw) = 1 - 2/(1+2^x)
__device__ __forceinline__ float tanh2(float x)  { return 1.0f - 2.0f * fast_rcp(1.0f + fast_ex2(x)); }

// ---- precompute: W_eff = (W_hh + W_ih @ W_fc) * gate_scale (f16),
//                  b_eff = (b_ih+b_hh+W_ih@b_fc) * gate_scale (f32)
__global__ __launch_bounds__(256)
void weff_kernel(const float* __restrict__ W_ih, const float* __restrict__ W_hh,
                 const float* __restrict__ b_ih, const float* __restrict__ b_hh,
                 const float* __restrict__ W_fc, const float* __restrict__ b_fc,
                 _Float16* __restrict__ w_eff, float* __restrict__ b_eff)
{
    const int idx = blockIdx.x * 256 + threadIdx.x;   // 4H*H = 65536 total
    const int n = idx >> 7, k = idx & 127;
    const float sg = ((n >> 7) == 2) ? 2.0f * LOG2E : LOG2E;
    float s = W_hh[n * HID + k];
    #pragma unroll
    for (int f = 0; f < NF; ++f) s += W_ih[n * NF + f] * W_fc[f * HID + k];
    w_eff[n * HID + k] = (_Float16)(s * sg);
    if (k == 0) {
        float bb = b_ih[n] + b_hh[n];
        #pragma unroll
        for (int f = 0; f < NF; ++f) bb += W_ih[n * NF + f] * b_fc[f];
        b_eff[n] = bb * sg;
    }
}

// 512 thr / 8 waves / 8 seqs / 256 WGs (1 per CU). Each wave owns 16 units x
// ALL 4 gates (Bf[4][4] h-weights in regs, x-weights in LDS): 20 MFMA/step.
// Seqs at z-rows 2s -> C row 4q = seq 2q (reg 0), row 4q+2 = seq 2q+1 (reg 2):
// each lane holds BOTH its cells' 4 gates in acc[g][0]/acc[g][2] -> LSTM
// epilogue is fully in-register (r9's gbuf LDS gate-exchange deleted, and its
// 2nd barrier with it). z double-buffered (r3-style): read z[p], write z[1-p],
// ONE barrier/step. launch_bounds(512,1): arg2=blocks/CU empirically (r5/r6),
// grid=1 WG/CU -> 256-reg cap, no spill risk (~120 needed).
__global__ __launch_bounds__(512, 1)
void lstm_encdec_kernel(const float* __restrict__ X,
                        const float* __restrict__ W_ih,
                        const float* __restrict__ W_hh,
                        const float* __restrict__ b_ih,
                        const float* __restrict__ b_hh,
                        const float* __restrict__ W_fc,
                        const float* __restrict__ b_fc,
                        const _Float16* __restrict__ w_eff,
                        const float* __restrict__ b_eff,
                        float* __restrict__ out)
{
    // z = [h(128)|x(13 pad 32)] per seq at row 2s; double-buffered.
    __shared__ _Float16 zbuf[2][16 * ZSTRIDE];      // 14848 B
    __shared__ half8 xw[2048];                      // [gw][g][lane] x-B frags, 32 KB
    __shared__ half8 wfcl[256];                     // [ks][lane] W_fc frags, 4 KB

    const int tid  = threadIdx.x;
    const int gw   = tid >> 6;            // wave 0..7 == unit-group
    const int lane = tid & 63;
    const int quad = lane >> 4;           // 0..3
    const int lcol = lane & 15;
    const int u    = gw * 16 + lcol;      // hidden unit 0..127
    const int seq0 = blockIdx.x * SEQS;

    // ---- per-wave B fragments: h-part of all 4 gates (exp2-prescaled) ----
    half8 Bf[4][4];
    float bb[4];
    #pragma unroll
    for (int g2 = 0; g2 < 4; ++g2) {
        const int n = g2 * HID + u;
        const float sg = (g2 == 2) ? 2.0f * LOG2E : LOG2E;
        #pragma unroll
        for (int ks = 0; ks < 4; ++ks) {
            const float* pw = W_hh + n * HID + ks * 32 + quad * 8;
            half8 v;
            #pragma unroll
            for (int j = 0; j < 8; ++j) v[j] = (_Float16)(pw[j] * sg);
            Bf[g2][ks] = v;
        }
        bb[g2] = (b_ih[n] + b_hh[n]) * sg;
    }
    const float bfc = (lcol < NF) ? b_fc[lcol] : 0.0f;

    // ---- stage x-weight fragments in LDS: entry (gw,g,lane), 2048 x 16B ----
    for (int idx = tid; idx < 2048; idx += 512) {
        const int lane_i = idx & 63, g_i = (idx >> 6) & 3, gw_i = idx >> 8;
        const int quad_i = lane_i >> 4, lcol_i = lane_i & 15;
        const int n = g_i * HID + gw_i * 16 + lcol_i;
        const float sg_i = (g_i == 2) ? 2.0f * LOG2E : LOG2E;
        half8 v;
        #pragma unroll
        for (int j = 0; j < 8; ++j) {
            const int kk = quad_i * 8 + j;
            v[j] = (kk < NF) ? (_Float16)(W_ih[n * NF + kk] * sg_i) : (_Float16)0.0f;
        }
        xw[idx] = v;
    }
    // ---- stage W_fc fragments: entry (ks,lane), 256 x 16B ----
    if (tid < 256) {
        const int lane_i = tid & 63, ks_i = tid >> 6;
        const int quad_i = lane_i >> 4, lcol_i = lane_i & 15;
        half8 v;
        #pragma unroll
        for (int j = 0; j < 8; ++j)
            v[j] = (lcol_i < NF)
                 ? (_Float16)W_fc[lcol_i * HID + ks_i * 32 + quad_i * 8 + j]
                 : (_Float16)0.0f;
        wfcl[tid] = v;
    }

    // ---- zero both z bufs (odd rows + x pads stay zero), then x_0 ----
    for (int i = tid; i < 2 * 16 * ZSTRIDE; i += 512)
        ((_Float16*)zbuf)[i] = (_Float16)0.0f;
    __syncthreads();
    const bool xact = tid < SEQS * NF;                // 104 loader threads
    const int  xs = tid / NF, xf = tid % NF;
    const long xbase = (long)(seq0 + xs) * SLEN * NF + xf;
    if (xact) zbuf[0][(2 * xs) * ZSTRIDE + HID + xf] = (_Float16)X[xbase];
    __syncthreads();

    float creg0 = 0.0f, creg1 = 0.0f, h0 = 0.0f, h1 = 0.0f;
    int p = 0;

    // GATES_CORE: a[] from z[p], 16 (or 20 with x) MFMA; a[], acc stay in scope
#define GATES_CORE(WX)                                                         \
    half8 a[5];                                                                \
    _Pragma("unroll")                                                          \
    for (int ks = 0; ks < 4; ++ks)                                             \
        a[ks] = *(const half8*)&zbuf[p][lcol * ZSTRIDE + ks * 32 + quad * 8];  \
    floatx4 acc[4];                                                            \
    _Pragma("unroll")                                                          \
    for (int g2 = 0; g2 < 4; ++g2) {                                           \
        floatx4 ci = (floatx4){bb[g2], bb[g2], bb[g2], bb[g2]};                \
        acc[g2] = __builtin_amdgcn_mfma_f32_16x16x32_f16(a[0], Bf[g2][0], ci, 0, 0, 0); \
    }                                                                          \
    _Pragma("unroll")                                                          \
    for (int ks = 1; ks < 4; ++ks)                                             \
        _Pragma("unroll")                                                      \
        for (int g2 = 0; g2 < 4; ++g2)                                         \
            acc[g2] = __builtin_amdgcn_mfma_f32_16x16x32_f16(a[ks], Bf[g2][ks], acc[g2], 0, 0, 0); \
    if (WX) {                                                                  \
        a[4] = *(const half8*)&zbuf[p][lcol * ZSTRIDE + HID + quad * 8];       \
        _Pragma("unroll")                                                      \
        for (int g2 = 0; g2 < 4; ++g2)                                         \
            acc[g2] = __builtin_amdgcn_mfma_f32_16x16x32_f16(a[4], xw[(gw * 4 + g2) * 64 + lane], acc[g2], 0, 0, 0); \
    }

    // in-register epilogue: 2 cells/thread (seqs 2q, 2q+1; unit u) -> z[1-p]
#define EPI_BODY                                                               \
    {                                                                          \
        float c0 = sigm2(acc[1][0]) * creg0 + sigm2(acc[0][0]) * tanh2(acc[2][0]); \
        creg0 = c0;                                                            \
        h0 = sigm2(acc[3][0]) * tanh2(c0 * (2.0f * LOG2E));                    \
        float c1 = sigm2(acc[1][2]) * creg1 + sigm2(acc[0][2]) * tanh2(acc[2][2]); \
        creg1 = c1;                                                            \
        h1 = sigm2(acc[3][2]) * tanh2(c1 * (2.0f * LOG2E));                    \
        zbuf[1 - p][(4 * quad) * ZSTRIDE + u]     = (_Float16)h0;              \
        zbuf[1 - p][(4 * quad + 2) * ZSTRIDE + u] = (_Float16)h1;              \
    }

    // ===================== encoder: 128 steps, 1 barrier/step =====================
    for (int t = 0; t < SLEN; ++t) {
        const int tn = (t + 1 < SLEN) ? t + 1 : SLEN - 1;
        float xpre = xact ? X[xbase + tn * NF] : 0.0f;

        GATES_CORE(1)
        EPI_BODY
        if (xact) zbuf[1 - p][(2 * xs) * ZSTRIDE + HID + xf] = (_Float16)xpre;
        __syncthreads();
        p ^= 1;
    }

    // embeddings = h_n
    out[(long)(seq0 + 2 * quad) * HID + u]     = h0;
    out[(long)(seq0 + 2 * quad + 1) * HID + u] = h1;

    float* dec = out + (long)NSEQ * HID;

    // ============ decoder step 0: real x_127 (5 K-steps, original weights) ========
    {
        GATES_CORE(1)
        EPI_BODY
        __syncthreads();
        p ^= 1;
    }

    // ---- swap to folded effective weights (16 dwordx4 loads) ----
    #pragma unroll
    for (int g2 = 0; g2 < 4; ++g2) {
        const int n = g2 * HID + u;
        #pragma unroll
        for (int ks = 0; ks < 4; ++ks)
            Bf[g2][ks] = *(const half8*)&w_eff[n * HID + ks * 32 + quad * 8];
        bb[g2] = b_eff[n];
    }

    // ====== decoder steps 1..127: 4 K-steps, 1 barrier, FC on wave 0 ==============
    for (int t = 1; t < SLEN; ++t) {
        GATES_CORE(0)

        // wave 0: dec[t-1] = FC(h_t); h_t IS a[0..3] (reuse, no extra LDS reads)
        if (gw == 0) {
            floatx4 o = (floatx4){bfc, bfc, bfc, bfc};
            #pragma unroll
            for (int ks = 0; ks < 4; ++ks)
                o = __builtin_amdgcn_mfma_f32_16x16x32_f16(a[ks], wfcl[ks * 64 + lane], o, 0, 0, 0);
            if (lcol < NF) {
                dec[(long)(seq0 + 2 * quad) * SLEN * NF + (t - 1) * NF + lcol]     = o[0];
                dec[(long)(seq0 + 2 * quad + 1) * SLEN * NF + (t - 1) * NF + lcol] = o[2];
            }
        }

        EPI_BODY
        __syncthreads();
        p ^= 1;
    }

    // ---- final dec output: dec[127] = FC(h_128) from last written buffer ----
    if (gw == 0) {
        half8 af[4];
        #pragma unroll
        for (int ks = 0; ks < 4; ++ks)
            af[ks] = *(const half8*)&zbuf[p][lcol * ZSTRIDE + ks * 32 + quad * 8];
        floatx4 o = (floatx4){bfc, bfc, bfc, bfc};
        #pragma unroll
        for (int ks = 0; ks < 4; ++ks)
            o = __builtin_amdgcn_mfma_f32_16x16x32_f16(af[ks], wfcl[ks * 64 + lane], o, 0, 0, 0);
        if (lcol < NF) {
            dec[(long)(seq0 + 2 * quad) * SLEN * NF + (SLEN - 1) * NF + lcol]     = o[0];
            dec[(long)(seq0 + 2 * quad + 1) * SLEN * NF + (SLEN - 1) * NF + lcol] = o[2];
        }
    }
}

extern "C" void kernel_launch(void* const* d_in, const int* in_sizes, int n_in,
                              void* d_out, int out_size, void* d_ws, size_t ws_size,
                              hipStream_t stream) {
    const float* X    = (const float*)d_in[0];
    const float* W_ih = (const float*)d_in[1];
    const float* W_hh = (const float*)d_in[2];
    const float* b_ih = (const float*)d_in[3];
    const float* b_hh = (const float*)d_in[4];
    const float* W_fc = (const float*)d_in[5];
    const float* b_fc = (const float*)d_in[6];
    float* out = (float*)d_out;

    _Float16* w_eff = (_Float16*)d_ws;                         // 4H*H f16 = 128 KiB
    float*    b_eff = (float*)((char*)d_ws + 4 * HID * HID * sizeof(_Float16));

    weff_kernel<<<(4 * HID * HID) / 256, 256, 0, stream>>>(
        W_ih, W_hh, b_ih, b_hh, W_fc, b_fc, w_eff, b_eff);

    lstm_encdec_kernel<<<NSEQ / SEQS, 512, 0, stream>>>(
        X, W_ih, W_hh, b_ih, b_hh, W_fc, b_fc, w_eff, b_eff, out);
}

// Round 13
// 241.755 us; speedup vs baseline: 1.6710x; 1.0209x over previous
//
#include <hip/hip_runtime.h>

#define HID 128
#define NF 13
#define SLEN 128
#define NSEQ 2048
#define SEQS 8            // seqs per WG
#define ZSTRIDE 236       // f16/row: 118 bank-words, gcd(22,32)=2 -> 2-way max
                          // (232 had gcd(20,32)=4 -> period-8 read aliasing + 4-way EPI writes)
#define LOG2E 1.44269504088896340736f

typedef _Float16 half8 __attribute__((ext_vector_type(8)));
typedef float floatx4 __attribute__((ext_vector_type(4)));

__device__ __forceinline__ float fast_rcp(float x) { return __builtin_amdgcn_rcpf(x); }
__device__ __forceinline__ float fast_ex2(float x) { return __builtin_amdgcn_exp2f(x); }
// gate pre-scaled by log2(e):  sigmoid(raw) = 1/(1+2^-x)
__device__ __forceinline__ float sigm2(float x)  { return fast_rcp(1.0f + fast_ex2(-x)); }
// gate pre-scaled by 2*log2(e): tanh(raw) = 1 - 2/(1+2^x)
__device__ __forceinline__ float tanh2(float x)  { return 1.0f - 2.0f * fast_rcp(1.0f + fast_ex2(x)); }

// ---- precompute: W_eff = (W_hh + W_ih @ W_fc) * gate_scale (f16),
//                  b_eff = (b_ih+b_hh+W_ih@b_fc) * gate_scale (f32)
__global__ __launch_bounds__(256)
void weff_kernel(const float* __restrict__ W_ih, const float* __restrict__ W_hh,
                 const float* __restrict__ b_ih, const float* __restrict__ b_hh,
                 const float* __restrict__ W_fc, const float* __restrict__ b_fc,
                 _Float16* __restrict__ w_eff, float* __restrict__ b_eff)
{
    const int idx = blockIdx.x * 256 + threadIdx.x;   // 4H*H = 65536 total
    const int n = idx >> 7, k = idx & 127;
    const float sg = ((n >> 7) == 2) ? 2.0f * LOG2E : LOG2E;
    float s = W_hh[n * HID + k];
    #pragma unroll
    for (int f = 0; f < NF; ++f) s += W_ih[n * NF + f] * W_fc[f * HID + k];
    w_eff[n * HID + k] = (_Float16)(s * sg);
    if (k == 0) {
        float bb = b_ih[n] + b_hh[n];
        #pragma unroll
        for (int f = 0; f < NF; ++f) bb += W_ih[n * NF + f] * b_fc[f];
        b_eff[n] = bb * sg;
    }
}

// r12 structure (best: 197us main): 512 thr / 8 waves / 8 seqs / 256 WGs,
// in-register gates (wave owns 16 units x all 4 gates), 1 barrier/step.
// This round: ZSTRIDE 236 (bank fix), 2-step unroll (static buffers),
// precomputed biasv, decoder-FC round-robin, x-write before EPI.
__global__ __launch_bounds__(512, 1)
void lstm_encdec_kernel(const float* __restrict__ X,
                        const float* __restrict__ W_ih,
                        const float* __restrict__ W_hh,
                        const float* __restrict__ b_ih,
                        const float* __restrict__ b_hh,
                        const float* __restrict__ W_fc,
                        const float* __restrict__ b_fc,
                        const _Float16* __restrict__ w_eff,
                        const float* __restrict__ b_eff,
                        float* __restrict__ out)
{
    // z = [h(128)|x(13 pad)] per seq at row 2s; double-buffered, static indices.
    __shared__ _Float16 zbuf[2][16 * ZSTRIDE];      // 15104 B
    __shared__ half8 xw[2048];                      // [gw][g][lane] x-B frags, 32 KB
    __shared__ half8 wfcl[256];                     // [ks][lane] W_fc frags, 4 KB

    const int tid  = threadIdx.x;
    const int gw   = tid >> 6;            // wave 0..7 == unit-group
    const int lane = tid & 63;
    const int quad = lane >> 4;           // 0..3
    const int lcol = lane & 15;
    const int u    = gw * 16 + lcol;      // hidden unit 0..127
    const int seq0 = blockIdx.x * SEQS;

    // ---- per-wave B fragments: h-part of all 4 gates (exp2-prescaled) ----
    half8 Bf[4][4];
    floatx4 biasv[4];
    #pragma unroll
    for (int g2 = 0; g2 < 4; ++g2) {
        const int n = g2 * HID + u;
        const float sg = (g2 == 2) ? 2.0f * LOG2E : LOG2E;
        #pragma unroll
        for (int ks = 0; ks < 4; ++ks) {
            const float* pw = W_hh + n * HID + ks * 32 + quad * 8;
            half8 v;
            #pragma unroll
            for (int j = 0; j < 8; ++j) v[j] = (_Float16)(pw[j] * sg);
            Bf[g2][ks] = v;
        }
        const float b = (b_ih[n] + b_hh[n]) * sg;
        biasv[g2] = (floatx4){b, b, b, b};
    }
    const float bfc = (lcol < NF) ? b_fc[lcol] : 0.0f;

    // ---- stage x-weight fragments in LDS: entry (gw,g,lane), 2048 x 16B ----
    for (int idx = tid; idx < 2048; idx += 512) {
        const int lane_i = idx & 63, g_i = (idx >> 6) & 3, gw_i = idx >> 8;
        const int quad_i = lane_i >> 4, lcol_i = lane_i & 15;
        const int n = g_i * HID + gw_i * 16 + lcol_i;
        const float sg_i = (g_i == 2) ? 2.0f * LOG2E : LOG2E;
        half8 v;
        #pragma unroll
        for (int j = 0; j < 8; ++j) {
            const int kk = quad_i * 8 + j;
            v[j] = (kk < NF) ? (_Float16)(W_ih[n * NF + kk] * sg_i) : (_Float16)0.0f;
        }
        xw[idx] = v;
    }
    // ---- stage W_fc fragments: entry (ks,lane), 256 x 16B ----
    if (tid < 256) {
        const int lane_i = tid & 63, ks_i = tid >> 6;
        const int quad_i = lane_i >> 4, lcol_i = lane_i & 15;
        half8 v;
        #pragma unroll
        for (int j = 0; j < 8; ++j)
            v[j] = (lcol_i < NF)
                 ? (_Float16)W_fc[lcol_i * HID + ks_i * 32 + quad_i * 8 + j]
                 : (_Float16)0.0f;
        wfcl[tid] = v;
    }

    // ---- zero both z bufs (odd rows + x pads stay zero), then x_0 ----
    for (int i = tid; i < 2 * 16 * ZSTRIDE; i += 512)
        ((_Float16*)zbuf)[i] = (_Float16)0.0f;
    __syncthreads();
    const bool xact = tid < SEQS * NF;                // 104 loader threads
    const int  xs = tid / NF, xf = tid % NF;
    const long xbase = (long)(seq0 + xs) * SLEN * NF + xf;
    if (xact) zbuf[0][(2 * xs) * ZSTRIDE + HID + xf] = (_Float16)X[xbase];
    __syncthreads();

    float creg0 = 0.0f, creg1 = 0.0f, h0 = 0.0f, h1 = 0.0f;

    // GATES_CORE(P,WX): a[] from zbuf[P] (static), 16 (or 20 with x) MFMA
#define GATES_CORE(P, WX)                                                      \
    half8 a[5];                                                                \
    _Pragma("unroll")                                                          \
    for (int ks = 0; ks < 4; ++ks)                                             \
        a[ks] = *(const half8*)&zbuf[P][lcol * ZSTRIDE + ks * 32 + quad * 8];  \
    floatx4 acc[4];                                                            \
    _Pragma("unroll")                                                          \
    for (int g2 = 0; g2 < 4; ++g2)                                             \
        acc[g2] = __builtin_amdgcn_mfma_f32_16x16x32_f16(a[0], Bf[g2][0], biasv[g2], 0, 0, 0); \
    _Pragma("unroll")                                                          \
    for (int ks = 1; ks < 4; ++ks)                                             \
        _Pragma("unroll")                                                      \
        for (int g2 = 0; g2 < 4; ++g2)                                         \
            acc[g2] = __builtin_amdgcn_mfma_f32_16x16x32_f16(a[ks], Bf[g2][ks], acc[g2], 0, 0, 0); \
    if (WX) {                                                                  \
        a[4] = *(const half8*)&zbuf[P][lcol * ZSTRIDE + HID + quad * 8];       \
        _Pragma("unroll")                                                      \
        for (int g2 = 0; g2 < 4; ++g2)                                         \
            acc[g2] = __builtin_amdgcn_mfma_f32_16x16x32_f16(a[4], xw[(gw * 4 + g2) * 64 + lane], acc[g2], 0, 0, 0); \
    }

    // in-register epilogue: 2 cells/thread (seqs 2q, 2q+1; unit u) -> zbuf[WP]
#define EPI_BODY(WP)                                                           \
    {                                                                          \
        float c0 = sigm2(acc[1][0]) * creg0 + sigm2(acc[0][0]) * tanh2(acc[2][0]); \
        creg0 = c0;                                                            \
        h0 = sigm2(acc[3][0]) * tanh2(c0 * (2.0f * LOG2E));                    \
        float c1 = sigm2(acc[1][2]) * creg1 + sigm2(acc[0][2]) * tanh2(acc[2][2]); \
        creg1 = c1;                                                            \
        h1 = sigm2(acc[3][2]) * tanh2(c1 * (2.0f * LOG2E));                    \
        zbuf[WP][(4 * quad) * ZSTRIDE + u]     = (_Float16)h0;                 \
        zbuf[WP][(4 * quad + 2) * ZSTRIDE + u] = (_Float16)h1;                 \
    }

    // encoder step: read buf RP, write buf WP; x-write before EPI (off the tail)
#define ESTEP(RP, WP, TT)                                                      \
    {                                                                          \
        const int tn = ((TT) + 1 < SLEN) ? (TT) + 1 : SLEN - 1;                \
        float xpre = xact ? X[xbase + tn * NF] : 0.0f;                         \
        GATES_CORE(RP, 1)                                                      \
        if (xact) zbuf[WP][(2 * xs) * ZSTRIDE + HID + xf] = (_Float16)xpre;    \
        EPI_BODY(WP)                                                           \
        __syncthreads();                                                       \
    }

    // ============ encoder: 128 steps, 2-step unrolled, 1 barrier/step ============
    for (int t = 0; t < SLEN; t += 2) {
        ESTEP(0, 1, t)
        ESTEP(1, 0, t + 1)
    }

    // embeddings = h_n
    out[(long)(seq0 + 2 * quad) * HID + u]     = h0;
    out[(long)(seq0 + 2 * quad + 1) * HID + u] = h1;

    float* dec = out + (long)NSEQ * HID;

    // ============ decoder step 0: real x_127 (5 K-steps, original weights) ========
    {
        GATES_CORE(0, 1)
        EPI_BODY(1)
        __syncthreads();
    }

    // ---- swap to folded effective weights (16 dwordx4 loads) ----
    #pragma unroll
    for (int g2 = 0; g2 < 4; ++g2) {
        const int n = g2 * HID + u;
        #pragma unroll
        for (int ks = 0; ks < 4; ++ks)
            Bf[g2][ks] = *(const half8*)&w_eff[n * HID + ks * 32 + quad * 8];
        const float b = b_eff[n];
        biasv[g2] = (floatx4){b, b, b, b};
    }

    // decoder step: FC round-robin (all waves hold identical a[]; wfcl is shared)
#define DSTEP(RP, WP, TT)                                                      \
    {                                                                          \
        GATES_CORE(RP, 0)                                                      \
        if (gw == (((TT) - 1) & 7)) {      /* dec[TT-1] = FC(h_TT), reuses a[] */ \
            floatx4 o = (floatx4){bfc, bfc, bfc, bfc};                         \
            _Pragma("unroll")                                                  \
            for (int ks = 0; ks < 4; ++ks)                                     \
                o = __builtin_amdgcn_mfma_f32_16x16x32_f16(a[ks], wfcl[ks * 64 + lane], o, 0, 0, 0); \
            if (lcol < NF) {                                                   \
                dec[(long)(seq0 + 2 * quad) * SLEN * NF + ((TT) - 1) * NF + lcol]     = o[0]; \
                dec[(long)(seq0 + 2 * quad + 1) * SLEN * NF + ((TT) - 1) * NF + lcol] = o[2]; \
            }                                                                  \
        }                                                                      \
        EPI_BODY(WP)                                                           \
        __syncthreads();                                                       \
    }

    // ====== decoder steps 1..127: 4 K-steps, 1 barrier, unrolled pairs ===========
    DSTEP(1, 0, 1)
    for (int t = 2; t < SLEN; t += 2) {
        DSTEP(0, 1, t)
        DSTEP(1, 0, t + 1)
    }
    // final h (after t=127, second of pair) is in buf 0

    // ---- final dec output: dec[127] = FC(h_128) ----
    if (gw == 7) {
        half8 af[4];
        #pragma unroll
        for (int ks = 0; ks < 4; ++ks)
            af[ks] = *(const half8*)&zbuf[0][lcol * ZSTRIDE + ks * 32 + quad * 8];
        floatx4 o = (floatx4){bfc, bfc, bfc, bfc};
        #pragma unroll
        for (int ks = 0; ks < 4; ++ks)
            o = __builtin_amdgcn_mfma_f32_16x16x32_f16(af[ks], wfcl[ks * 64 + lane], o, 0, 0, 0);
        if (lcol < NF) {
            dec[(long)(seq0 + 2 * quad) * SLEN * NF + (SLEN - 1) * NF + lcol]     = o[0];
            dec[(long)(seq0 + 2 * quad + 1) * SLEN * NF + (SLEN - 1) * NF + lcol] = o[2];
        }
    }
}

extern "C" void kernel_launch(void* const* d_in, const int* in_sizes, int n_in,
                              void* d_out, int out_size, void* d_ws, size_t ws_size,
                              hipStream_t stream) {
    const float* X    = (const float*)d_in[0];
    const float* W_ih = (const float*)d_in[1];
    const float* W_hh = (const float*)d_in[2];
    const float* b_ih = (const float*)d_in[3];
    const float* b_hh = (const float*)d_in[4];
    const float* W_fc = (const float*)d_in[5];
    const float* b_fc = (const float*)d_in[6];
    float* out = (float*)d_out;

    _Float16* w_eff = (_Float16*)d_ws;                         // 4H*H f16 = 128 KiB
    float*    b_eff = (float*)((char*)d_ws + 4 * HID * HID * sizeof(_Float16));

    weff_kernel<<<(4 * HID * HID) / 256, 256, 0, stream>>>(
        W_ih, W_hh, b_ih, b_hh, W_fc, b_fc, w_eff, b_eff);

    lstm_encdec_kernel<<<NSEQ / SEQS, 512, 0, stream>>>(
        X, W_ih, W_hh, b_ih, b_hh, W_fc, b_fc, w_eff, b_eff, out);
}

// Round 14
// 240.536 us; speedup vs baseline: 1.6795x; 1.0051x over previous
//
#include <hip/hip_runtime.h>

#define HID 128
#define NF 13
#define SLEN 128
#define NSEQ 2048
#define SEQS 8            // seqs per WG
#define ZSTRIDE 236       // f16/row: 118 bank-words, gcd(22,32)=2 -> 2-way max
#define LOG2E 1.44269504088896340736f

typedef _Float16 half8 __attribute__((ext_vector_type(8)));
typedef float floatx4 __attribute__((ext_vector_type(4)));

__device__ __forceinline__ float fast_rcp(float x) { return __builtin_amdgcn_rcpf(x); }
__device__ __forceinline__ float fast_ex2(float x) { return __builtin_amdgcn_exp2f(x); }
// gate pre-scaled by log2(e):  sigmoid(raw) = 1/(1+2^-x)
__device__ __forceinline__ float sigm2(float x)  { return fast_rcp(1.0f + fast_ex2(-x)); }
// gate pre-scaled by 2*log2(e): tanh(raw) = 1 - 2/(1+2^x)
__device__ __forceinline__ float tanh2(float x)  { return 1.0f - 2.0f * fast_rcp(1.0f + fast_ex2(x)); }

// ---- precompute: W_eff = (W_hh + W_ih @ W_fc) * gate_scale (f16),
//                  b_eff = (b_ih+b_hh+W_ih@b_fc) * gate_scale (f32)
__global__ __launch_bounds__(256)
void weff_kernel(const float* __restrict__ W_ih, const float* __restrict__ W_hh,
                 const float* __restrict__ b_ih, const float* __restrict__ b_hh,
                 const float* __restrict__ W_fc, const float* __restrict__ b_fc,
                 _Float16* __restrict__ w_eff, float* __restrict__ b_eff)
{
    const int idx = blockIdx.x * 256 + threadIdx.x;   // 4H*H = 65536 total
    const int n = idx >> 7, k = idx & 127;
    const float sg = ((n >> 7) == 2) ? 2.0f * LOG2E : LOG2E;
    float s = W_hh[n * HID + k];
    #pragma unroll
    for (int f = 0; f < NF; ++f) s += W_ih[n * NF + f] * W_fc[f * HID + k];
    w_eff[n * HID + k] = (_Float16)(s * sg);
    if (k == 0) {
        float bb = b_ih[n] + b_hh[n];
        #pragma unroll
        for (int f = 0; f < NF; ++f) bb += W_ih[n * NF + f] * b_fc[f];
        b_eff[n] = bb * sg;
    }
}

// r13 structure (best: 191.5us main, conflicts ~33K): 512 thr / 8 waves /
// 8 seqs / 256 WGs, in-register gates, 1 barrier/step, ZSTRIDE 236.
// This round: x-weight fragments moved LDS -> REGISTERS (Bf[4][5]). They are
// loop-invariant per wave; r13 re-read the same 4 half8 from LDS every encoder
// step (32 redundant ds_read_b128/WG-step in the post-barrier LDS burst).
// VGPR 84 -> ~100-108, still <=128 (2 waves/SIMD preserved, per r6's 108).
__global__ __launch_bounds__(512, 1)
void lstm_encdec_kernel(const float* __restrict__ X,
                        const float* __restrict__ W_ih,
                        const float* __restrict__ W_hh,
                        const float* __restrict__ b_ih,
                        const float* __restrict__ b_hh,
                        const float* __restrict__ W_fc,
                        const float* __restrict__ b_fc,
                        const _Float16* __restrict__ w_eff,
                        const float* __restrict__ b_eff,
                        float* __restrict__ out)
{
    // z = [h(128)|x(13 pad)] per seq at row 2s; double-buffered, static indices.
    __shared__ _Float16 zbuf[2][16 * ZSTRIDE];      // 15104 B
    __shared__ half8 wfcl[256];                     // [ks][lane] W_fc frags, 4 KB

    const int tid  = threadIdx.x;
    const int gw   = tid >> 6;            // wave 0..7 == unit-group
    const int lane = tid & 63;
    const int quad = lane >> 4;           // 0..3
    const int lcol = lane & 15;
    const int u    = gw * 16 + lcol;      // hidden unit 0..127
    const int seq0 = blockIdx.x * SEQS;

    // ---- per-wave B fragments: all 4 gates x (4 h K-steps + 1 x K-step) ----
    half8 Bf[4][5];
    floatx4 biasv[4];
    #pragma unroll
    for (int g2 = 0; g2 < 4; ++g2) {
        const int n = g2 * HID + u;
        const float sg = (g2 == 2) ? 2.0f * LOG2E : LOG2E;
        #pragma unroll
        for (int ks = 0; ks < 4; ++ks) {
            const float* pw = W_hh + n * HID + ks * 32 + quad * 8;
            half8 v;
            #pragma unroll
            for (int j = 0; j < 8; ++j) v[j] = (_Float16)(pw[j] * sg);
            Bf[g2][ks] = v;
        }
        {   // x part (K-step 4), kept in registers (loop-invariant per wave)
            half8 v;
            #pragma unroll
            for (int j = 0; j < 8; ++j) {
                const int kk = quad * 8 + j;
                v[j] = (kk < NF) ? (_Float16)(W_ih[n * NF + kk] * sg) : (_Float16)0.0f;
            }
            Bf[g2][4] = v;
        }
        const float b = (b_ih[n] + b_hh[n]) * sg;
        biasv[g2] = (floatx4){b, b, b, b};
    }
    const float bfc = (lcol < NF) ? b_fc[lcol] : 0.0f;

    // ---- stage W_fc fragments: entry (ks,lane), 256 x 16B ----
    if (tid < 256) {
        const int lane_i = tid & 63, ks_i = tid >> 6;
        const int quad_i = lane_i >> 4, lcol_i = lane_i & 15;
        half8 v;
        #pragma unroll
        for (int j = 0; j < 8; ++j)
            v[j] = (lcol_i < NF)
                 ? (_Float16)W_fc[lcol_i * HID + ks_i * 32 + quad_i * 8 + j]
                 : (_Float16)0.0f;
        wfcl[tid] = v;
    }

    // ---- zero both z bufs (odd rows + x pads stay zero), then x_0 ----
    for (int i = tid; i < 2 * 16 * ZSTRIDE; i += 512)
        ((_Float16*)zbuf)[i] = (_Float16)0.0f;
    __syncthreads();
    const bool xact = tid < SEQS * NF;                // 104 loader threads
    const int  xs = tid / NF, xf = tid % NF;
    const long xbase = (long)(seq0 + xs) * SLEN * NF + xf;
    if (xact) zbuf[0][(2 * xs) * ZSTRIDE + HID + xf] = (_Float16)X[xbase];
    __syncthreads();

    float creg0 = 0.0f, creg1 = 0.0f, h0 = 0.0f, h1 = 0.0f;

    // GATES_CORE(P,WX): a[] from zbuf[P] (static), 16 (or 20 with x) MFMA
#define GATES_CORE(P, WX)                                                      \
    half8 a[5];                                                                \
    _Pragma("unroll")                                                          \
    for (int ks = 0; ks < 4; ++ks)                                             \
        a[ks] = *(const half8*)&zbuf[P][lcol * ZSTRIDE + ks * 32 + quad * 8];  \
    floatx4 acc[4];                                                            \
    _Pragma("unroll")                                                          \
    for (int g2 = 0; g2 < 4; ++g2)                                             \
        acc[g2] = __builtin_amdgcn_mfma_f32_16x16x32_f16(a[0], Bf[g2][0], biasv[g2], 0, 0, 0); \
    _Pragma("unroll")                                                          \
    for (int ks = 1; ks < 4; ++ks)                                             \
        _Pragma("unroll")                                                      \
        for (int g2 = 0; g2 < 4; ++g2)                                         \
            acc[g2] = __builtin_amdgcn_mfma_f32_16x16x32_f16(a[ks], Bf[g2][ks], acc[g2], 0, 0, 0); \
    if (WX) {                                                                  \
        a[4] = *(const half8*)&zbuf[P][lcol * ZSTRIDE + HID + quad * 8];       \
        _Pragma("unroll")                                                      \
        for (int g2 = 0; g2 < 4; ++g2)                                         \
            acc[g2] = __builtin_amdgcn_mfma_f32_16x16x32_f16(a[4], Bf[g2][4], acc[g2], 0, 0, 0); \
    }

    // in-register epilogue: 2 cells/thread (seqs 2q, 2q+1; unit u) -> zbuf[WP]
#define EPI_BODY(WP)                                                           \
    {                                                                          \
        float c0 = sigm2(acc[1][0]) * creg0 + sigm2(acc[0][0]) * tanh2(acc[2][0]); \
        creg0 = c0;                                                            \
        h0 = sigm2(acc[3][0]) * tanh2(c0 * (2.0f * LOG2E));                    \
        float c1 = sigm2(acc[1][2]) * creg1 + sigm2(acc[0][2]) * tanh2(acc[2][2]); \
        creg1 = c1;                                                            \
        h1 = sigm2(acc[3][2]) * tanh2(c1 * (2.0f * LOG2E));                    \
        zbuf[WP][(4 * quad) * ZSTRIDE + u]     = (_Float16)h0;                 \
        zbuf[WP][(4 * quad + 2) * ZSTRIDE + u] = (_Float16)h1;                 \
    }

    // encoder step: read buf RP, write buf WP; x-write before EPI (off the tail)
#define ESTEP(RP, WP, TT)                                                      \
    {                                                                          \
        const int tn = ((TT) + 1 < SLEN) ? (TT) + 1 : SLEN - 1;                \
        float xpre = xact ? X[xbase + tn * NF] : 0.0f;                         \
        GATES_CORE(RP, 1)                                                      \
        if (xact) zbuf[WP][(2 * xs) * ZSTRIDE + HID + xf] = (_Float16)xpre;    \
        EPI_BODY(WP)                                                           \
        __syncthreads();                                                       \
    }

    // ============ encoder: 128 steps, 2-step unrolled, 1 barrier/step ============
    for (int t = 0; t < SLEN; t += 2) {
        ESTEP(0, 1, t)
        ESTEP(1, 0, t + 1)
    }

    // embeddings = h_n
    out[(long)(seq0 + 2 * quad) * HID + u]     = h0;
    out[(long)(seq0 + 2 * quad + 1) * HID + u] = h1;

    float* dec = out + (long)NSEQ * HID;

    // ============ decoder step 0: real x_127 (5 K-steps, original weights) ========
    {
        GATES_CORE(0, 1)
        EPI_BODY(1)
        __syncthreads();
    }

    // ---- swap to folded effective weights (16 dwordx4 loads) ----
    #pragma unroll
    for (int g2 = 0; g2 < 4; ++g2) {
        const int n = g2 * HID + u;
        #pragma unroll
        for (int ks = 0; ks < 4; ++ks)
            Bf[g2][ks] = *(const half8*)&w_eff[n * HID + ks * 32 + quad * 8];
        const float b = b_eff[n];
        biasv[g2] = (floatx4){b, b, b, b};
    }

    // decoder step: FC round-robin (all waves hold identical a[]; wfcl is shared)
#define DSTEP(RP, WP, TT)                                                      \
    {                                                                          \
        GATES_CORE(RP, 0)                                                      \
        if (gw == (((TT) - 1) & 7)) {      /* dec[TT-1] = FC(h_TT), reuses a[] */ \
            floatx4 o = (floatx4){bfc, bfc, bfc, bfc};                         \
            _Pragma("unroll")                                                  \
            for (int ks = 0; ks < 4; ++ks)                                     \
                o = __builtin_amdgcn_mfma_f32_16x16x32_f16(a[ks], wfcl[ks * 64 + lane], o, 0, 0, 0); \
            if (lcol < NF) {                                                   \
                dec[(long)(seq0 + 2 * quad) * SLEN * NF + ((TT) - 1) * NF + lcol]     = o[0]; \
                dec[(long)(seq0 + 2 * quad + 1) * SLEN * NF + ((TT) - 1) * NF + lcol] = o[2]; \
            }                                                                  \
        }                                                                      \
        EPI_BODY(WP)                                                           \
        __syncthreads();                                                       \
    }

    // ====== decoder steps 1..127: 4 K-steps, 1 barrier, unrolled pairs ===========
    DSTEP(1, 0, 1)
    for (int t = 2; t < SLEN; t += 2) {
        DSTEP(0, 1, t)
        DSTEP(1, 0, t + 1)
    }
    // final h (after t=127, second of pair) is in buf 0

    // ---- final dec output: dec[127] = FC(h_128) ----
    if (gw == 7) {
        half8 af[4];
        #pragma unroll
        for (int ks = 0; ks < 4; ++ks)
            af[ks] = *(const half8*)&zbuf[0][lcol * ZSTRIDE + ks * 32 + quad * 8];
        floatx4 o = (floatx4){bfc, bfc, bfc, bfc};
        #pragma unroll
        for (int ks = 0; ks < 4; ++ks)
            o = __builtin_amdgcn_mfma_f32_16x16x32_f16(af[ks], wfcl[ks * 64 + lane], o, 0, 0, 0);
        if (lcol < NF) {
            dec[(long)(seq0 + 2 * quad) * SLEN * NF + (SLEN - 1) * NF + lcol]     = o[0];
            dec[(long)(seq0 + 2 * quad + 1) * SLEN * NF + (SLEN - 1) * NF + lcol] = o[2];
        }
    }
}

extern "C" void kernel_launch(void* const* d_in, const int* in_sizes, int n_in,
                              void* d_out, int out_size, void* d_ws, size_t ws_size,
                              hipStream_t stream) {
    const float* X    = (const float*)d_in[0];
    const float* W_ih = (const float*)d_in[1];
    const float* W_hh = (const float*)d_in[2];
    const float* b_ih = (const float*)d_in[3];
    const float* b_hh = (const float*)d_in[4];
    const float* W_fc = (const float*)d_in[5];
    const float* b_fc = (const float*)d_in[6];
    float* out = (float*)d_out;

    _Float16* w_eff = (_Float16*)d_ws;                         // 4H*H f16 = 128 KiB
    float*    b_eff = (float*)((char*)d_ws + 4 * HID * HID * sizeof(_Float16));

    weff_kernel<<<(4 * HID * HID) / 256, 256, 0, stream>>>(
        W_ih, W_hh, b_ih, b_hh, W_fc, b_fc, w_eff, b_eff);

    lstm_encdec_kernel<<<NSEQ / SEQS, 512, 0, stream>>>(
        X, W_ih, W_hh, b_ih, b_hh, W_fc, b_fc, w_eff, b_eff, out);
}

// Round 15
// 237.769 us; speedup vs baseline: 1.6990x; 1.0116x over previous
//
#include <hip/hip_runtime.h>

#define HID 128
#define NF 13
#define SLEN 128
#define NSEQ 2048
#define SEQS 8            // seqs per WG
#define ZSTRIDE 236       // f16/row: 118 bank-words, gcd(22,32)=2 -> 2-way max
#define LOG2E 1.44269504088896340736f

typedef _Float16 half8 __attribute__((ext_vector_type(8)));
typedef float floatx4 __attribute__((ext_vector_type(4)));

__device__ __forceinline__ float fast_rcp(float x) { return __builtin_amdgcn_rcpf(x); }
__device__ __forceinline__ float fast_ex2(float x) { return __builtin_amdgcn_exp2f(x); }
// gate pre-scaled by log2(e):  sigmoid(raw) = 1/(1+2^-x)
__device__ __forceinline__ float sigm2(float x)  { return fast_rcp(1.0f + fast_ex2(-x)); }
// gate pre-scaled by 2*log2(e): tanh(raw) = 1 - 2/(1+2^x)
__device__ __forceinline__ float tanh2(float x)  { return 1.0f - 2.0f * fast_rcp(1.0f + fast_ex2(x)); }

// Light barrier: __syncthreads() emits s_waitcnt vmcnt(0) lgkmcnt(0) before
// s_barrier, draining the decoder's dec[] global stores (never read in-kernel)
// and the encoder's X prefetch loads at EVERY step. Inter-wave communication
// here is LDS-only -> lgkmcnt(0) suffices; global loads are auto-waited at
// their register use. sched_barrier(0) fences compiler reordering (rule #18).
#define LIGHT_SYNC()                                                           \
    do {                                                                       \
        asm volatile("s_waitcnt lgkmcnt(0)\n\ts_barrier" ::: "memory");        \
        __builtin_amdgcn_sched_barrier(0);                                     \
    } while (0)

// ---- precompute: W_eff = (W_hh + W_ih @ W_fc) * gate_scale (f16),
//                  b_eff = (b_ih+b_hh+W_ih@b_fc) * gate_scale (f32)
__global__ __launch_bounds__(256)
void weff_kernel(const float* __restrict__ W_ih, const float* __restrict__ W_hh,
                 const float* __restrict__ b_ih, const float* __restrict__ b_hh,
                 const float* __restrict__ W_fc, const float* __restrict__ b_fc,
                 _Float16* __restrict__ w_eff, float* __restrict__ b_eff)
{
    const int idx = blockIdx.x * 256 + threadIdx.x;   // 4H*H = 65536 total
    const int n = idx >> 7, k = idx & 127;
    const float sg = ((n >> 7) == 2) ? 2.0f * LOG2E : LOG2E;
    float s = W_hh[n * HID + k];
    #pragma unroll
    for (int f = 0; f < NF; ++f) s += W_ih[n * NF + f] * W_fc[f * HID + k];
    w_eff[n * HID + k] = (_Float16)(s * sg);
    if (k == 0) {
        float bb = b_ih[n] + b_hh[n];
        #pragma unroll
        for (int f = 0; f < NF; ++f) bb += W_ih[n * NF + f] * b_fc[f];
        b_eff[n] = bb * sg;
    }
}

// r14 structure (best: 189us main): 512 thr / 8 waves / 8 seqs / 256 WGs,
// in-register gates + x-weights, 1 barrier/step, ZSTRIDE 236, conflicts ~33K.
// This round: in-loop barriers lightened to lgkmcnt(0)-only (see LIGHT_SYNC).
__global__ __launch_bounds__(512, 1)
void lstm_encdec_kernel(const float* __restrict__ X,
                        const float* __restrict__ W_ih,
                        const float* __restrict__ W_hh,
                        const float* __restrict__ b_ih,
                        const float* __restrict__ b_hh,
                        const float* __restrict__ W_fc,
                        const float* __restrict__ b_fc,
                        const _Float16* __restrict__ w_eff,
                        const float* __restrict__ b_eff,
                        float* __restrict__ out)
{
    // z = [h(128)|x(13 pad)] per seq at row 2s; double-buffered, static indices.
    __shared__ _Float16 zbuf[2][16 * ZSTRIDE];      // 15104 B
    __shared__ half8 wfcl[256];                     // [ks][lane] W_fc frags, 4 KB

    const int tid  = threadIdx.x;
    const int gw   = tid >> 6;            // wave 0..7 == unit-group
    const int lane = tid & 63;
    const int quad = lane >> 4;           // 0..3
    const int lcol = lane & 15;
    const int u    = gw * 16 + lcol;      // hidden unit 0..127
    const int seq0 = blockIdx.x * SEQS;

    // ---- per-wave B fragments: all 4 gates x (4 h K-steps + 1 x K-step) ----
    half8 Bf[4][5];
    floatx4 biasv[4];
    #pragma unroll
    for (int g2 = 0; g2 < 4; ++g2) {
        const int n = g2 * HID + u;
        const float sg = (g2 == 2) ? 2.0f * LOG2E : LOG2E;
        #pragma unroll
        for (int ks = 0; ks < 4; ++ks) {
            const float* pw = W_hh + n * HID + ks * 32 + quad * 8;
            half8 v;
            #pragma unroll
            for (int j = 0; j < 8; ++j) v[j] = (_Float16)(pw[j] * sg);
            Bf[g2][ks] = v;
        }
        {   // x part (K-step 4), kept in registers (loop-invariant per wave)
            half8 v;
            #pragma unroll
            for (int j = 0; j < 8; ++j) {
                const int kk = quad * 8 + j;
                v[j] = (kk < NF) ? (_Float16)(W_ih[n * NF + kk] * sg) : (_Float16)0.0f;
            }
            Bf[g2][4] = v;
        }
        const float b = (b_ih[n] + b_hh[n]) * sg;
        biasv[g2] = (floatx4){b, b, b, b};
    }
    const float bfc = (lcol < NF) ? b_fc[lcol] : 0.0f;

    // ---- stage W_fc fragments: entry (ks,lane), 256 x 16B ----
    if (tid < 256) {
        const int lane_i = tid & 63, ks_i = tid >> 6;
        const int quad_i = lane_i >> 4, lcol_i = lane_i & 15;
        half8 v;
        #pragma unroll
        for (int j = 0; j < 8; ++j)
            v[j] = (lcol_i < NF)
                 ? (_Float16)W_fc[lcol_i * HID + ks_i * 32 + quad_i * 8 + j]
                 : (_Float16)0.0f;
        wfcl[tid] = v;
    }

    // ---- zero both z bufs (odd rows + x pads stay zero), then x_0 ----
    for (int i = tid; i < 2 * 16 * ZSTRIDE; i += 512)
        ((_Float16*)zbuf)[i] = (_Float16)0.0f;
    __syncthreads();
    const bool xact = tid < SEQS * NF;                // 104 loader threads
    const int  xs = tid / NF, xf = tid % NF;
    const long xbase = (long)(seq0 + xs) * SLEN * NF + xf;
    if (xact) zbuf[0][(2 * xs) * ZSTRIDE + HID + xf] = (_Float16)X[xbase];
    __syncthreads();

    float creg0 = 0.0f, creg1 = 0.0f, h0 = 0.0f, h1 = 0.0f;

    // GATES_CORE(P,WX): a[] from zbuf[P] (static), 16 (or 20 with x) MFMA
#define GATES_CORE(P, WX)                                                      \
    half8 a[5];                                                                \
    _Pragma("unroll")                                                          \
    for (int ks = 0; ks < 4; ++ks)                                             \
        a[ks] = *(const half8*)&zbuf[P][lcol * ZSTRIDE + ks * 32 + quad * 8];  \
    floatx4 acc[4];                                                            \
    _Pragma("unroll")                                                          \
    for (int g2 = 0; g2 < 4; ++g2)                                             \
        acc[g2] = __builtin_amdgcn_mfma_f32_16x16x32_f16(a[0], Bf[g2][0], biasv[g2], 0, 0, 0); \
    _Pragma("unroll")                                                          \
    for (int ks = 1; ks < 4; ++ks)                                             \
        _Pragma("unroll")                                                      \
        for (int g2 = 0; g2 < 4; ++g2)                                         \
            acc[g2] = __builtin_amdgcn_mfma_f32_16x16x32_f16(a[ks], Bf[g2][ks], acc[g2], 0, 0, 0); \
    if (WX) {                                                                  \
        a[4] = *(const half8*)&zbuf[P][lcol * ZSTRIDE + HID + quad * 8];       \
        _Pragma("unroll")                                                      \
        for (int g2 = 0; g2 < 4; ++g2)                                         \
            acc[g2] = __builtin_amdgcn_mfma_f32_16x16x32_f16(a[4], Bf[g2][4], acc[g2], 0, 0, 0); \
    }

    // in-register epilogue: 2 cells/thread (seqs 2q, 2q+1; unit u) -> zbuf[WP]
#define EPI_BODY(WP)                                                           \
    {                                                                          \
        float c0 = sigm2(acc[1][0]) * creg0 + sigm2(acc[0][0]) * tanh2(acc[2][0]); \
        creg0 = c0;                                                            \
        h0 = sigm2(acc[3][0]) * tanh2(c0 * (2.0f * LOG2E));                    \
        float c1 = sigm2(acc[1][2]) * creg1 + sigm2(acc[0][2]) * tanh2(acc[2][2]); \
        creg1 = c1;                                                            \
        h1 = sigm2(acc[3][2]) * tanh2(c1 * (2.0f * LOG2E));                    \
        zbuf[WP][(4 * quad) * ZSTRIDE + u]     = (_Float16)h0;                 \
        zbuf[WP][(4 * quad + 2) * ZSTRIDE + u] = (_Float16)h1;                 \
    }

    // encoder step: read buf RP, write buf WP; x-write before EPI (off the tail)
#define ESTEP(RP, WP, TT)                                                      \
    {                                                                          \
        const int tn = ((TT) + 1 < SLEN) ? (TT) + 1 : SLEN - 1;                \
        float xpre = xact ? X[xbase + tn * NF] : 0.0f;                         \
        GATES_CORE(RP, 1)                                                      \
        if (xact) zbuf[WP][(2 * xs) * ZSTRIDE + HID + xf] = (_Float16)xpre;    \
        EPI_BODY(WP)                                                           \
        LIGHT_SYNC();                                                          \
    }

    // ============ encoder: 128 steps, 2-step unrolled, 1 light barrier/step ======
    for (int t = 0; t < SLEN; t += 2) {
        ESTEP(0, 1, t)
        ESTEP(1, 0, t + 1)
    }

    // embeddings = h_n
    out[(long)(seq0 + 2 * quad) * HID + u]     = h0;
    out[(long)(seq0 + 2 * quad + 1) * HID + u] = h1;

    float* dec = out + (long)NSEQ * HID;

    // ============ decoder step 0: real x_127 (5 K-steps, original weights) ========
    {
        GATES_CORE(0, 1)
        EPI_BODY(1)
        LIGHT_SYNC();
    }

    // ---- swap to folded effective weights (16 dwordx4 loads) ----
    #pragma unroll
    for (int g2 = 0; g2 < 4; ++g2) {
        const int n = g2 * HID + u;
        #pragma unroll
        for (int ks = 0; ks < 4; ++ks)
            Bf[g2][ks] = *(const half8*)&w_eff[n * HID + ks * 32 + quad * 8];
        const float b = b_eff[n];
        biasv[g2] = (floatx4){b, b, b, b};
    }

    // decoder step: FC round-robin (all waves hold identical a[]; wfcl is shared)
#define DSTEP(RP, WP, TT)                                                      \
    {                                                                          \
        GATES_CORE(RP, 0)                                                      \
        if (gw == (((TT) - 1) & 7)) {      /* dec[TT-1] = FC(h_TT), reuses a[] */ \
            floatx4 o = (floatx4){bfc, bfc, bfc, bfc};                         \
            _Pragma("unroll")                                                  \
            for (int ks = 0; ks < 4; ++ks)                                     \
                o = __builtin_amdgcn_mfma_f32_16x16x32_f16(a[ks], wfcl[ks * 64 + lane], o, 0, 0, 0); \
            if (lcol < NF) {                                                   \
                dec[(long)(seq0 + 2 * quad) * SLEN * NF + ((TT) - 1) * NF + lcol]     = o[0]; \
                dec[(long)(seq0 + 2 * quad + 1) * SLEN * NF + ((TT) - 1) * NF + lcol] = o[2]; \
            }                                                                  \
        }                                                                      \
        EPI_BODY(WP)                                                           \
        LIGHT_SYNC();                                                          \
    }

    // ====== decoder steps 1..127: 4 K-steps, 1 light barrier, unrolled pairs =====
    DSTEP(1, 0, 1)
    for (int t = 2; t < SLEN; t += 2) {
        DSTEP(0, 1, t)
        DSTEP(1, 0, t + 1)
    }
    // final h (after t=127, second of pair) is in buf 0

    // ---- final dec output: dec[127] = FC(h_128) ----
    if (gw == 7) {
        half8 af[4];
        #pragma unroll
        for (int ks = 0; ks < 4; ++ks)
            af[ks] = *(const half8*)&zbuf[0][lcol * ZSTRIDE + ks * 32 + quad * 8];
        floatx4 o = (floatx4){bfc, bfc, bfc, bfc};
        #pragma unroll
        for (int ks = 0; ks < 4; ++ks)
            o = __builtin_amdgcn_mfma_f32_16x16x32_f16(af[ks], wfcl[ks * 64 + lane], o, 0, 0, 0);
        if (lcol < NF) {
            dec[(long)(seq0 + 2 * quad) * SLEN * NF + (SLEN - 1) * NF + lcol]     = o[0];
            dec[(long)(seq0 + 2 * quad + 1) * SLEN * NF + (SLEN - 1) * NF + lcol] = o[2];
        }
    }
}

extern "C" void kernel_launch(void* const* d_in, const int* in_sizes, int n_in,
                              void* d_out, int out_size, void* d_ws, size_t ws_size,
                              hipStream_t stream) {
    const float* X    = (const float*)d_in[0];
    const float* W_ih = (const float*)d_in[1];
    const float* W_hh = (const float*)d_in[2];
    const float* b_ih = (const float*)d_in[3];
    const float* b_hh = (const float*)d_in[4];
    const float* W_fc = (const float*)d_in[5];
    const float* b_fc = (const float*)d_in[6];
    float* out = (float*)d_out;

    _Float16* w_eff = (_Float16*)d_ws;                         // 4H*H f16 = 128 KiB
    float*    b_eff = (float*)((char*)d_ws + 4 * HID * HID * sizeof(_Float16));

    weff_kernel<<<(4 * HID * HID) / 256, 256, 0, stream>>>(
        W_ih, W_hh, b_ih, b_hh, W_fc, b_fc, w_eff, b_eff);

    lstm_encdec_kernel<<<NSEQ / SEQS, 512, 0, stream>>>(
        X, W_ih, W_hh, b_ih, b_hh, W_fc, b_fc, w_eff, b_eff, out);
}